// Round 3
// baseline (313.537 us; speedup 1.0000x reference)
//
#include <hip/hip_runtime.h>

#define NB 4
#define NC 256
#define NCK 32
#define NPIX 4096
#define TOT (NB * NC * NPIX)

typedef unsigned short u16;
typedef unsigned int u32;
typedef __bf16 bfv8 __attribute__((ext_vector_type(8)));
typedef float f32x4 __attribute__((ext_vector_type(4)));

__device__ inline u16 f2bf(float f) {
  union { float f; u32 u; } v; v.f = f;
  u32 r = v.u + 0x7fffu + ((v.u >> 16) & 1u);  // RNE
  return (u16)(r >> 16);
}
__device__ inline float bf2f(u16 h) {
  union { u32 u; float f; } v; v.u = (u32)h << 16; return v.f;
}

// ---------------- K1: convert Wh (fp32 256x256) -> bf16 ----------------
__global__ __launch_bounds__(256) void k_convert_wh(const float* __restrict__ Wh,
                                                    u16* __restrict__ Whbf) {
  int i = (blockIdx.x * 256 + threadIdx.x) * 4;
  float4 v = *(const float4*)(Wh + i);
  u32 lo = (u32)f2bf(v.x) | ((u32)f2bf(v.y) << 16);
  u32 hi = (u32)f2bf(v.z) | ((u32)f2bf(v.w) << 16);
  *(uint2*)(Whbf + i) = make_uint2(lo, hi);
}

// ---------------- K2: transpose x [B,C,N] fp32 -> xT [B,N,C] bf16 ----------------
__global__ __launch_bounds__(256) void k_transpose(const float* __restrict__ x,
                                                   u16* __restrict__ xT) {
  __shared__ float tile[64][65];
  int blk = blockIdx.x;
  int b = blk >> 8, r = blk & 255;
  int nt = r >> 2, ct = r & 3;
  int t = threadIdx.x;
  int cc = t >> 2, part = t & 3;
  const float* src = x + ((size_t)(b * NC + ct * 64 + cc)) * NPIX + nt * 64 + part * 16;
#pragma unroll
  for (int v = 0; v < 4; v++) {
    float4 d = *(const float4*)(src + v * 4);
    tile[cc][part * 16 + v * 4 + 0] = d.x;
    tile[cc][part * 16 + v * 4 + 1] = d.y;
    tile[cc][part * 16 + v * 4 + 2] = d.z;
    tile[cc][part * 16 + v * 4 + 3] = d.w;
  }
  __syncthreads();
  int n = t >> 2;
  u32 uu[8];
#pragma unroll
  for (int q = 0; q < 8; q++) {
    u16 e0 = f2bf(tile[part * 16 + 2 * q + 0][n]);
    u16 e1 = f2bf(tile[part * 16 + 2 * q + 1][n]);
    uu[q] = (u32)e0 | ((u32)e1 << 16);
  }
  u16* dst = xT + ((size_t)(b * NPIX + nt * 64 + n)) * NC + ct * 64 + part * 16;
  *(uint4*)(dst) = make_uint4(uu[0], uu[1], uu[2], uu[3]);
  *(uint4*)(dst + 8) = make_uint4(uu[4], uu[5], uu[6], uu[7]);
}

// ---------------- K3: f,g projections -> packed hi/lo bf16, K-contiguous ----------------
__global__ __launch_bounds__(256) void k_fg(const float* __restrict__ x,
                                            const float* __restrict__ Wf,
                                            const float* __restrict__ bf_,
                                            const float* __restrict__ Wg,
                                            const float* __restrict__ bg_,
                                            u16* __restrict__ fT,
                                            u16* __restrict__ gT) {
  __shared__ float Wt[256][65];
  __shared__ float xl[32][64];
  __shared__ float tb[64][68];
  int blk = blockIdx.x;
  int b = blk >> 6;
  int n0 = (blk & 63) * 64;
  int t = threadIdx.x;
  int tx = t & 15, ty = t >> 4;
  for (int r = 0; r < 64; r++) {
    float w = (r < 32) ? Wf[r * 256 + t] : Wg[(r - 32) * 256 + t];
    Wt[t][r] = w;
  }
  float acc[4][4] = {};
  for (int kc = 0; kc < 8; kc++) {
    __syncthreads();
#pragma unroll
    for (int r = 0; r < 2; r++) {
      int e = (r * 256 + t) * 4;
      int row = e >> 6, col = e & 63;
      *(float4*)&xl[row][col] =
          *(const float4*)(x + ((size_t)(b * NC + kc * 32 + row)) * NPIX + n0 + col);
    }
    __syncthreads();
#pragma unroll
    for (int kk = 0; kk < 32; kk++) {
      float4 xv = *(const float4*)&xl[kk][tx * 4];
      float w0 = Wt[kc * 32 + kk][ty * 4 + 0];
      float w1 = Wt[kc * 32 + kk][ty * 4 + 1];
      float w2 = Wt[kc * 32 + kk][ty * 4 + 2];
      float w3 = Wt[kc * 32 + kk][ty * 4 + 3];
      acc[0][0] += w0 * xv.x; acc[0][1] += w0 * xv.y; acc[0][2] += w0 * xv.z; acc[0][3] += w0 * xv.w;
      acc[1][0] += w1 * xv.x; acc[1][1] += w1 * xv.y; acc[1][2] += w1 * xv.z; acc[1][3] += w1 * xv.w;
      acc[2][0] += w2 * xv.x; acc[2][1] += w2 * xv.y; acc[2][2] += w2 * xv.z; acc[2][3] += w2 * xv.w;
      acc[3][0] += w3 * xv.x; acc[3][1] += w3 * xv.y; acc[3][2] += w3 * xv.z; acc[3][3] += w3 * xv.w;
    }
  }
#pragma unroll
  for (int j = 0; j < 4; j++) {
    int o = ty * 4 + j;
    float bias = (o < 32) ? bf_[o] : bg_[o - 32];
#pragma unroll
    for (int vi = 0; vi < 4; vi++) tb[tx * 4 + vi][o] = acc[j][vi] + bias;
  }
  __syncthreads();
  int n = t >> 2, part = t & 3;
  {
    u32 ph[4], plo[4];
#pragma unroll
    for (int e = 0; e < 4; e++) {
      float v0 = tb[n][part * 8 + 2 * e + 0];
      float v1 = tb[n][part * 8 + 2 * e + 1];
      u16 h0 = f2bf(v0), h1 = f2bf(v1);
      u16 l0 = f2bf(v0 - bf2f(h0)), l1 = f2bf(v1 - bf2f(h1));
      ph[e] = (u32)h0 | ((u32)h1 << 16);
      plo[e] = (u32)l0 | ((u32)l1 << 16);
    }
    u16* dst = fT + ((size_t)(b * NPIX) + n0 + n) * 64 + part * 8;
    *(uint4*)dst = make_uint4(ph[0], ph[1], ph[2], ph[3]);
    *(uint4*)(dst + 32) = make_uint4(plo[0], plo[1], plo[2], plo[3]);
  }
  {
    u32 ph[4], plo[4];
#pragma unroll
    for (int e = 0; e < 4; e++) {
      float v0 = tb[n][32 + part * 8 + 2 * e + 0];
      float v1 = tb[n][32 + part * 8 + 2 * e + 1];
      u16 h0 = f2bf(v0), h1 = f2bf(v1);
      u16 l0 = f2bf(v0 - bf2f(h0)), l1 = f2bf(v1 - bf2f(h1));
      ph[e] = (u32)h0 | ((u32)h1 << 16);
      plo[e] = (u32)l0 | ((u32)l1 << 16);
    }
    u16* dst = gT + ((size_t)(b * NPIX) + n0 + n) * 64 + part * 8;
    *(uint4*)dst = make_uint4(ph[0], ph[1], ph[2], ph[3]);
    *(uint4*)(dst + 32) = make_uint4(plo[0], plo[1], plo[2], plo[3]);
  }
}

// ---------------- K4: h projection (bf16 MFMA GEMM) ----------------
__global__ __launch_bounds__(256) void k_h(const u16* __restrict__ xT,
                                           const u16* __restrict__ Whbf,
                                           const float* __restrict__ bh,
                                           u16* __restrict__ h) {
  __shared__ u16 At[128 * 32];
  __shared__ u16 Bt[128 * 32];
  int blk = blockIdx.x;
  int b = blk >> 6, r = blk & 63;
  int nt = r >> 1, ot = r & 1;
  int n0 = nt * 128, o0 = ot * 128;
  int t = threadIdx.x, lane = t & 63, w = t >> 6;
  int wr = w >> 1, wc = w & 1;
  int coll = lane & 15, cg = lane >> 4;
  f32x4 acc[4][4] = {};
  for (int kc = 0; kc < 8; kc++) {
    __syncthreads();
#pragma unroll
    for (int r2 = 0; r2 < 2; r2++) {
      int s = r2 * 256 + t;
      int row = s >> 2, slot = s & 3;
      int sw = (row ^ (row >> 2)) & 3;
      uint4 va = *(const uint4*)(xT + ((size_t)(b * NPIX + n0 + row)) * NC + kc * 32 + slot * 8);
      *(uint4*)((char*)At + row * 64 + ((slot ^ sw) * 16)) = va;
      uint4 vb = *(const uint4*)(Whbf + (size_t)(o0 + row) * NC + kc * 32 + slot * 8);
      *(uint4*)((char*)Bt + row * 64 + ((slot ^ sw) * 16)) = vb;
    }
    __syncthreads();
    bfv8 af[4], bfr[4];
#pragma unroll
    for (int mi = 0; mi < 4; mi++) {
      int row = wr * 64 + mi * 16 + coll;
      int slot = cg ^ ((row ^ (row >> 2)) & 3);
      af[mi] = *(const bfv8*)((const char*)At + row * 64 + slot * 16);
    }
#pragma unroll
    for (int ni = 0; ni < 4; ni++) {
      int row = wc * 64 + ni * 16 + coll;
      int slot = cg ^ ((row ^ (row >> 2)) & 3);
      bfr[ni] = *(const bfv8*)((const char*)Bt + row * 64 + slot * 16);
    }
#pragma unroll
    for (int mi = 0; mi < 4; mi++)
#pragma unroll
      for (int ni = 0; ni < 4; ni++)
        acc[mi][ni] = __builtin_amdgcn_mfma_f32_16x16x32_bf16(af[mi], bfr[ni], acc[mi][ni], 0, 0, 0);
  }
#pragma unroll
  for (int ni = 0; ni < 4; ni++) {
    int o = o0 + wc * 64 + ni * 16 + coll;
    float bias = bh[o];
#pragma unroll
    for (int mi = 0; mi < 4; mi++) {
      int px = n0 + wr * 64 + mi * 16 + cg * 4;
      u32 lo = (u32)f2bf(acc[mi][ni][0] + bias) | ((u32)f2bf(acc[mi][ni][1] + bias) << 16);
      u32 hi = (u32)f2bf(acc[mi][ni][2] + bias) | ((u32)f2bf(acc[mi][ni][3] + bias) << 16);
      *(uint2*)(h + ((size_t)(b * NC + o)) * NPIX + px) = make_uint2(lo, hi);
    }
  }
}

// ---------------- K5: pass 1 partials — per (b, j-tile, i-slice): m,d ----------------
__global__ __launch_bounds__(256) void k_pass1(const u16* __restrict__ fT,
                                               const u16* __restrict__ gT,
                                               float2* __restrict__ pmd) {
  __shared__ u16 gs[64 * 64];
  int blk = blockIdx.x;
  int iq = blk & 7, jt = (blk >> 3) & 63, b = blk >> 9;
  int j0 = jt * 64, ibase = iq * 512;
  int t = threadIdx.x, lane = t & 63, w = t >> 6;
  int coll = lane & 15, cg = lane >> 4;
  const u16* fr = fT + ((size_t)(b * NPIX) + j0 + w * 16 + coll) * 64 + cg * 8;
  bfv8 ah = *(const bfv8*)fr;
  bfv8 al = *(const bfv8*)(fr + 32);
  float m[4] = {-3e38f, -3e38f, -3e38f, -3e38f}, d[4] = {0.f, 0.f, 0.f, 0.f};
  int r0 = t >> 3, s0 = t & 7;
  uint4 v0 = *(const uint4*)(gT + ((size_t)(b * NPIX) + ibase + r0) * 64 + s0 * 8);
  uint4 v1 = *(const uint4*)(gT + ((size_t)(b * NPIX) + ibase + 32 + r0) * 64 + s0 * 8);
  for (int it2 = 0; it2 < 8; ++it2) {
    __syncthreads();
    *(uint4*)(&gs[r0 * 64 + ((s0 ^ (r0 & 7)) << 3)]) = v0;
    *(uint4*)(&gs[(32 + r0) * 64 + ((s0 ^ (r0 & 7)) << 3)]) = v1;
    __syncthreads();
    if (it2 < 7) {
      v0 = *(const uint4*)(gT + ((size_t)(b * NPIX) + ibase + (it2 + 1) * 64 + r0) * 64 + s0 * 8);
      v1 = *(const uint4*)(gT + ((size_t)(b * NPIX) + ibase + (it2 + 1) * 64 + 32 + r0) * 64 + s0 * 8);
    }
    float sv[4][4];
#pragma unroll
    for (int t4 = 0; t4 < 4; ++t4) {
      int row = t4 * 16 + coll;
      const u16* base = &gs[row * 64];
      bfv8 bh = *(const bfv8*)(base + ((cg ^ (row & 7)) << 3));
      bfv8 bl = *(const bfv8*)(base + (((4 + cg) ^ (row & 7)) << 3));
      f32x4 s = {0.f, 0.f, 0.f, 0.f};
      s = __builtin_amdgcn_mfma_f32_16x16x32_bf16(al, bh, s, 0, 0, 0);
      s = __builtin_amdgcn_mfma_f32_16x16x32_bf16(ah, bl, s, 0, 0, 0);
      s = __builtin_amdgcn_mfma_f32_16x16x32_bf16(ah, bh, s, 0, 0, 0);
      sv[t4][0] = s[0]; sv[t4][1] = s[1]; sv[t4][2] = s[2]; sv[t4][3] = s[3];
    }
#pragma unroll
    for (int r = 0; r < 4; ++r) {
      float ms = fmaxf(fmaxf(sv[0][r], sv[1][r]), fmaxf(sv[2][r], sv[3][r]));
      float nm = fmaxf(m[r], ms);
      d[r] = d[r] * __expf(m[r] - nm) + __expf(sv[0][r] - nm) + __expf(sv[1][r] - nm) +
             __expf(sv[2][r] - nm) + __expf(sv[3][r] - nm);
      m[r] = nm;
    }
  }
#pragma unroll
  for (int r = 0; r < 4; ++r) {
#pragma unroll
    for (int off = 1; off < 16; off <<= 1) {
      float m2 = __shfl_xor(m[r], off);
      float d2 = __shfl_xor(d[r], off);
      float nm = fmaxf(m[r], m2);
      d[r] = d[r] * __expf(m[r] - nm) + d2 * __expf(m2 - nm);
      m[r] = nm;
    }
  }
  if (coll == 0) {
#pragma unroll
    for (int r = 0; r < 4; ++r) {
      int j = j0 + w * 16 + cg * 4 + r;
      pmd[((size_t)(b * 8 + iq)) * NPIX + j] = make_float2(m[r], d[r]);
    }
  }
}

// ---------------- K5b: combine 8 i-slice partials -> (M, 1/D) ----------------
__global__ __launch_bounds__(256) void k_comb(const float2* __restrict__ pmd,
                                              float2* __restrict__ md2) {
  int idx = blockIdx.x * 256 + threadIdx.x;  // 16384
  int b = idx >> 12, j = idx & 4095;
  float2 p[8];
  float M = -3e38f;
#pragma unroll
  for (int q = 0; q < 8; ++q) {
    p[q] = pmd[((size_t)(b * 8 + q)) * NPIX + j];
    M = fmaxf(M, p[q].x);
  }
  float D = 0.f;
#pragma unroll
  for (int q = 0; q < 8; ++q) D += p[q].y * __expf(p[q].x - M);
  md2[idx] = make_float2(M, 1.0f / D);
}

// ---------------- K6: pass 2 partial — Opart[jq][b,c,i] (bf16) ----------------
__global__ __launch_bounds__(256, 4) void k_pass2(const u16* __restrict__ fT,
                                                  const u16* __restrict__ gT,
                                                  const u16* __restrict__ h,
                                                  const float2* __restrict__ md2,
                                                  u16* __restrict__ Opart) {
  __shared__ char smem[25088];
  u16* vt = (u16*)smem;                 // [128c][64j] swizzled, 16KB
  u16* pl = (u16*)(smem + 16384);       // [4w][16i][64j] swizzled, 8KB
  float2* mdl = (float2*)(smem + 24576);  // [64 j]
  float* tb = (float*)smem;             // epilogue alias (64*65*4 = 16.6KB)
  int blk = blockIdx.x;
  int jq = blk & 1, chh = (blk >> 1) & 1, it = (blk >> 2) & 63, b = blk >> 8;
  int i0 = it * 64, ch0 = chh * 128, jbase = jq * 2048;
  int t = threadIdx.x, lane = t & 63, w = t >> 6;
  int coll = lane & 15, cg = lane >> 4;
  // g B-frags for this wave's i-subtile (fixed)
  const u16* gr = gT + ((size_t)(b * NPIX) + i0 + w * 16 + coll) * 64 + cg * 8;
  bfv8 gh = *(const bfv8*)gr;
  bfv8 gl = *(const bfv8*)(gr + 32);
  f32x4 acc[8] = {};
  uint4 hv[4];
  float2 mpre = make_float2(0.f, 0.f);
  int hrow = t >> 3, hslot = t & 7;
#pragma unroll
  for (int q = 0; q < 4; ++q) {
    int row = q * 32 + hrow;
    hv[q] = *(const uint4*)(h + ((size_t)(b * NC) + ch0 + row) * NPIX + jbase + hslot * 8);
  }
  if (t < 64) mpre = md2[b * NPIX + jbase + t];
  // f A-frags, loop-carried
  bfv8 ah[4], al[4];
#pragma unroll
  for (int jt2 = 0; jt2 < 4; ++jt2) {
    const u16* fr2 = fT + ((size_t)(b * NPIX) + jbase + jt2 * 16 + coll) * 64 + cg * 8;
    ah[jt2] = *(const bfv8*)fr2;
    al[jt2] = *(const bfv8*)(fr2 + 32);
  }
  for (int jc = 0; jc < 32; ++jc) {
    int j1 = jbase + (jc + 1) * 64;
    __syncthreads();
#pragma unroll
    for (int q = 0; q < 4; ++q) {
      int row = q * 32 + hrow;
      *(uint4*)(&vt[row * 64 + ((hslot ^ (row & 7)) << 3)]) = hv[q];
    }
    if (t < 64) mdl[t] = mpre;
    __syncthreads();
    if (jc < 31) {
#pragma unroll
      for (int q = 0; q < 4; ++q) {
        int row = q * 32 + hrow;
        hv[q] = *(const uint4*)(h + ((size_t)(b * NC) + ch0 + row) * NPIX + j1 + hslot * 8);
      }
      if (t < 64) mpre = md2[b * NPIX + j1 + t];
    }
    // QK per j-subtile: 3 MFMA -> reload frags for next iter -> exp -> P^T to LDS
#pragma unroll
    for (int jt2 = 0; jt2 < 4; ++jt2) {
      f32x4 s = {0.f, 0.f, 0.f, 0.f};
      s = __builtin_amdgcn_mfma_f32_16x16x32_bf16(al[jt2], gh, s, 0, 0, 0);
      s = __builtin_amdgcn_mfma_f32_16x16x32_bf16(ah[jt2], gl, s, 0, 0, 0);
      s = __builtin_amdgcn_mfma_f32_16x16x32_bf16(ah[jt2], gh, s, 0, 0, 0);
      if (jc < 31) {
        const u16* fr2 = fT + ((size_t)(b * NPIX) + j1 + jt2 * 16 + coll) * 64 + cg * 8;
        ah[jt2] = *(const bfv8*)fr2;
        al[jt2] = *(const bfv8*)(fr2 + 32);
      }
      int jr = jt2 * 16 + cg * 4;
      float2 m0 = mdl[jr + 0], m1 = mdl[jr + 1], m2 = mdl[jr + 2], m3 = mdl[jr + 3];
      float p0 = __expf(s[0] - m0.x) * m0.y;
      float p1 = __expf(s[1] - m1.x) * m1.y;
      float p2 = __expf(s[2] - m2.x) * m2.y;
      float p3 = __expf(s[3] - m3.x) * m3.y;
      u32 pk0 = (u32)f2bf(p0) | ((u32)f2bf(p1) << 16);
      u32 pk1 = (u32)f2bf(p2) | ((u32)f2bf(p3) << 16);
      char* pb = (char*)&pl[w * 1024] + coll * 128;
      *(uint2*)(pb + ((jt2 * 32 + cg * 8) ^ ((coll & 7) << 4))) = make_uint2(pk0, pk1);
    }
    // PV
    bfv8 pa[2];
#pragma unroll
    for (int kb = 0; kb < 2; ++kb) {
      const char* pb = (const char*)&pl[w * 1024] + coll * 128;
      pa[kb] = *(const bfv8*)(pb + ((kb * 64 + cg * 16) ^ ((coll & 7) << 4)));
    }
#pragma unroll
    for (int ct = 0; ct < 8; ++ct) {
      int row = ct * 16 + coll;
      const char* vb = (const char*)vt + row * 128;
      int sw = (row & 7) << 4;
#pragma unroll
      for (int kb = 0; kb < 2; ++kb) {
        bfv8 bv = *(const bfv8*)(vb + ((kb * 64 + cg * 16) ^ sw));
        acc[ct] = __builtin_amdgcn_mfma_f32_16x16x32_bf16(pa[kb], bv, acc[ct], 0, 0, 0);
      }
    }
  }
  // epilogue: transpose in LDS, write bf16 partials
  for (int ch = 0; ch < 2; ++ch) {
    __syncthreads();
#pragma unroll
    for (int q2 = 0; q2 < 4; ++q2)
#pragma unroll
      for (int rr = 0; rr < 4; ++rr)
        tb[(w * 16 + cg * 4 + rr) * 65 + q2 * 16 + coll] = acc[ch * 4 + q2][rr];
    __syncthreads();
    int crow = t >> 2, part = t & 3;
    u16* op = Opart + (size_t)jq * TOT +
              ((size_t)(b * NC) + ch0 + ch * 64 + crow) * NPIX + i0 + part * 16;
#pragma unroll
    for (int v = 0; v < 4; ++v) {
      float s0 = tb[(part * 16 + v * 4 + 0) * 65 + crow];
      float s1 = tb[(part * 16 + v * 4 + 1) * 65 + crow];
      float s2 = tb[(part * 16 + v * 4 + 2) * 65 + crow];
      float s3 = tb[(part * 16 + v * 4 + 3) * 65 + crow];
      u32 lo = (u32)f2bf(s0) | ((u32)f2bf(s1) << 16);
      u32 hi = (u32)f2bf(s2) | ((u32)f2bf(s3) << 16);
      *(uint2*)(op + v * 4) = make_uint2(lo, hi);
    }
  }
}

// ---------------- K7: reduce partials + residual ----------------
__global__ __launch_bounds__(256) void k_reduce(const u16* __restrict__ Opart,
                                                const float* __restrict__ x,
                                                const float* __restrict__ gamma,
                                                float* __restrict__ out) {
  int i = (blockIdx.x * 256 + threadIdx.x) * 4;
  uint2 a = *(const uint2*)(Opart + i);
  uint2 c = *(const uint2*)(Opart + TOT + i);
  float4 xv = *(const float4*)(x + i);
  float gam = gamma[0];
  float4 ov;
  ov.x = gam * (bf2f((u16)(a.x & 0xffff)) + bf2f((u16)(c.x & 0xffff))) + xv.x;
  ov.y = gam * (bf2f((u16)(a.x >> 16)) + bf2f((u16)(c.x >> 16))) + xv.y;
  ov.z = gam * (bf2f((u16)(a.y & 0xffff)) + bf2f((u16)(c.y & 0xffff))) + xv.z;
  ov.w = gam * (bf2f((u16)(a.y >> 16)) + bf2f((u16)(c.y >> 16))) + xv.w;
  *(float4*)(out + i) = ov;
}

extern "C" void kernel_launch(void* const* d_in, const int* in_sizes, int n_in,
                              void* d_out, int out_size, void* d_ws, size_t ws_size,
                              hipStream_t stream) {
  (void)in_sizes; (void)n_in; (void)out_size; (void)ws_size;
  const float* x = (const float*)d_in[0];
  const float* Wf = (const float*)d_in[1];
  const float* bf_ = (const float*)d_in[2];
  const float* Wg = (const float*)d_in[3];
  const float* bg_ = (const float*)d_in[4];
  const float* Wh = (const float*)d_in[5];
  const float* bh = (const float*)d_in[6];
  const float* gamma = (const float*)d_in[7];
  float* out = (float*)d_out;
  char* ws = (char*)d_ws;
  const size_t M1 = 1u << 20;
  // [0, 16.78M): xT (first 8MB; dead after k_h) then reused as Opart (2x bf16 partials)
  u16* xT = (u16*)ws;
  u16* Opart = (u16*)ws;
  u16* h = (u16*)(ws + 17 * M1);
  u16* fT = (u16*)(ws + 25 * M1);
  u16* gT = (u16*)(ws + 27 * M1);
  float2* md2 = (float2*)(ws + 29 * M1);                       // 128KB
  float2* pmd = (float2*)(ws + 29 * M1 + (1u << 17));          // 1MB
  u16* Whbf = (u16*)(ws + 29 * M1 + (1u << 17) + (1u << 20));  // 128KB

  k_convert_wh<<<64, 256, 0, stream>>>(Wh, Whbf);
  k_transpose<<<1024, 256, 0, stream>>>(x, xT);
  k_fg<<<256, 256, 0, stream>>>(x, Wf, bf_, Wg, bg_, fT, gT);
  k_h<<<256, 256, 0, stream>>>(xT, Whbf, bh, h);
  k_pass1<<<2048, 256, 0, stream>>>(fT, gT, pmd);
  k_comb<<<64, 256, 0, stream>>>(pmd, md2);
  k_pass2<<<1024, 256, 0, stream>>>(fT, gT, h, md2, Opart);
  k_reduce<<<4096, 256, 0, stream>>>(Opart, x, gamma, out);
}

// Round 4
// 297.111 us; speedup vs baseline: 1.0553x; 1.0553x over previous
//
#include <hip/hip_runtime.h>

#define NB 4
#define NC 256
#define NCK 32
#define NPIX 4096
#define TOT (NB * NC * NPIX)

typedef unsigned short u16;
typedef unsigned int u32;
typedef __bf16 bfv8 __attribute__((ext_vector_type(8)));
typedef float f32x4 __attribute__((ext_vector_type(4)));
#define LOG2E 1.4426950408889634f

__device__ inline u16 f2bf(float f) {
  union { float f; u32 u; } v; v.f = f;
  u32 r = v.u + 0x7fffu + ((v.u >> 16) & 1u);  // RNE
  return (u16)(r >> 16);
}
__device__ inline float bf2f(u16 h) {
  union { u32 u; float f; } v; v.u = (u32)h << 16; return v.f;
}
__device__ inline u32 cvtpk(float a, float b) {
  u32 r;
  asm("v_cvt_pk_bf16_f32 %0, %1, %2" : "=v"(r) : "v"(a), "v"(b));
  return r;
}

// ---------------- K1: convert Wh (fp32 256x256) -> bf16 ----------------
__global__ __launch_bounds__(256) void k_convert_wh(const float* __restrict__ Wh,
                                                    u16* __restrict__ Whbf) {
  int i = (blockIdx.x * 256 + threadIdx.x) * 4;
  float4 v = *(const float4*)(Wh + i);
  *(uint2*)(Whbf + i) = make_uint2(cvtpk(v.x, v.y), cvtpk(v.z, v.w));
}

// ---------------- K2: transpose x [B,C,N] fp32 -> xT [B,N,C] bf16 ----------------
__global__ __launch_bounds__(256) void k_transpose(const float* __restrict__ x,
                                                   u16* __restrict__ xT) {
  __shared__ float tile[64][65];
  int blk = blockIdx.x;
  int b = blk >> 8, r = blk & 255;
  int nt = r >> 2, ct = r & 3;
  int t = threadIdx.x;
  int cc = t >> 2, part = t & 3;
  const float* src = x + ((size_t)(b * NC + ct * 64 + cc)) * NPIX + nt * 64 + part * 16;
#pragma unroll
  for (int v = 0; v < 4; v++) {
    float4 d = *(const float4*)(src + v * 4);
    tile[cc][part * 16 + v * 4 + 0] = d.x;
    tile[cc][part * 16 + v * 4 + 1] = d.y;
    tile[cc][part * 16 + v * 4 + 2] = d.z;
    tile[cc][part * 16 + v * 4 + 3] = d.w;
  }
  __syncthreads();
  int n = t >> 2;
  u32 uu[8];
#pragma unroll
  for (int q = 0; q < 8; q++)
    uu[q] = cvtpk(tile[part * 16 + 2 * q + 0][n], tile[part * 16 + 2 * q + 1][n]);
  u16* dst = xT + ((size_t)(b * NPIX + nt * 64 + n)) * NC + ct * 64 + part * 16;
  *(uint4*)(dst) = make_uint4(uu[0], uu[1], uu[2], uu[3]);
  *(uint4*)(dst + 8) = make_uint4(uu[4], uu[5], uu[6], uu[7]);
}

// ---------------- K3: f,g projections -> packed hi/lo bf16, K-contiguous ----------------
__global__ __launch_bounds__(256) void k_fg(const float* __restrict__ x,
                                            const float* __restrict__ Wf,
                                            const float* __restrict__ bf_,
                                            const float* __restrict__ Wg,
                                            const float* __restrict__ bg_,
                                            u16* __restrict__ fT,
                                            u16* __restrict__ gT) {
  __shared__ float Wt[256][65];
  __shared__ float xl[32][64];
  __shared__ float tb[64][68];
  int blk = blockIdx.x;
  int b = blk >> 6;
  int n0 = (blk & 63) * 64;
  int t = threadIdx.x;
  int tx = t & 15, ty = t >> 4;
  for (int r = 0; r < 64; r++) {
    float w = (r < 32) ? Wf[r * 256 + t] : Wg[(r - 32) * 256 + t];
    Wt[t][r] = w;
  }
  float acc[4][4] = {};
  for (int kc = 0; kc < 8; kc++) {
    __syncthreads();
#pragma unroll
    for (int r = 0; r < 2; r++) {
      int e = (r * 256 + t) * 4;
      int row = e >> 6, col = e & 63;
      *(float4*)&xl[row][col] =
          *(const float4*)(x + ((size_t)(b * NC + kc * 32 + row)) * NPIX + n0 + col);
    }
    __syncthreads();
#pragma unroll
    for (int kk = 0; kk < 32; kk++) {
      float4 xv = *(const float4*)&xl[kk][tx * 4];
      float w0 = Wt[kc * 32 + kk][ty * 4 + 0];
      float w1 = Wt[kc * 32 + kk][ty * 4 + 1];
      float w2 = Wt[kc * 32 + kk][ty * 4 + 2];
      float w3 = Wt[kc * 32 + kk][ty * 4 + 3];
      acc[0][0] += w0 * xv.x; acc[0][1] += w0 * xv.y; acc[0][2] += w0 * xv.z; acc[0][3] += w0 * xv.w;
      acc[1][0] += w1 * xv.x; acc[1][1] += w1 * xv.y; acc[1][2] += w1 * xv.z; acc[1][3] += w1 * xv.w;
      acc[2][0] += w2 * xv.x; acc[2][1] += w2 * xv.y; acc[2][2] += w2 * xv.z; acc[2][3] += w2 * xv.w;
      acc[3][0] += w3 * xv.x; acc[3][1] += w3 * xv.y; acc[3][2] += w3 * xv.z; acc[3][3] += w3 * xv.w;
    }
  }
#pragma unroll
  for (int j = 0; j < 4; j++) {
    int o = ty * 4 + j;
    float bias = (o < 32) ? bf_[o] : bg_[o - 32];
#pragma unroll
    for (int vi = 0; vi < 4; vi++) tb[tx * 4 + vi][o] = acc[j][vi] + bias;
  }
  __syncthreads();
  int n = t >> 2, part = t & 3;
  {
    u32 ph[4], plo[4];
#pragma unroll
    for (int e = 0; e < 4; e++) {
      float v0 = tb[n][part * 8 + 2 * e + 0];
      float v1 = tb[n][part * 8 + 2 * e + 1];
      u16 h0 = f2bf(v0), h1 = f2bf(v1);
      u16 l0 = f2bf(v0 - bf2f(h0)), l1 = f2bf(v1 - bf2f(h1));
      ph[e] = (u32)h0 | ((u32)h1 << 16);
      plo[e] = (u32)l0 | ((u32)l1 << 16);
    }
    u16* dst = fT + ((size_t)(b * NPIX) + n0 + n) * 64 + part * 8;
    *(uint4*)dst = make_uint4(ph[0], ph[1], ph[2], ph[3]);
    *(uint4*)(dst + 32) = make_uint4(plo[0], plo[1], plo[2], plo[3]);
  }
  {
    u32 ph[4], plo[4];
#pragma unroll
    for (int e = 0; e < 4; e++) {
      float v0 = tb[n][32 + part * 8 + 2 * e + 0];
      float v1 = tb[n][32 + part * 8 + 2 * e + 1];
      u16 h0 = f2bf(v0), h1 = f2bf(v1);
      u16 l0 = f2bf(v0 - bf2f(h0)), l1 = f2bf(v1 - bf2f(h1));
      ph[e] = (u32)h0 | ((u32)h1 << 16);
      plo[e] = (u32)l0 | ((u32)l1 << 16);
    }
    u16* dst = gT + ((size_t)(b * NPIX) + n0 + n) * 64 + part * 8;
    *(uint4*)dst = make_uint4(ph[0], ph[1], ph[2], ph[3]);
    *(uint4*)(dst + 32) = make_uint4(plo[0], plo[1], plo[2], plo[3]);
  }
}

// ---------------- K4: h projection (bf16 MFMA GEMM) ----------------
__global__ __launch_bounds__(256) void k_h(const u16* __restrict__ xT,
                                           const u16* __restrict__ Whbf,
                                           const float* __restrict__ bh,
                                           u16* __restrict__ h) {
  __shared__ u16 At[128 * 32];
  __shared__ u16 Bt[128 * 32];
  int blk = blockIdx.x;
  int b = blk >> 6, r = blk & 63;
  int nt = r >> 1, ot = r & 1;
  int n0 = nt * 128, o0 = ot * 128;
  int t = threadIdx.x, lane = t & 63, w = t >> 6;
  int wr = w >> 1, wc = w & 1;
  int coll = lane & 15, cg = lane >> 4;
  f32x4 acc[4][4] = {};
  for (int kc = 0; kc < 8; kc++) {
    __syncthreads();
#pragma unroll
    for (int r2 = 0; r2 < 2; r2++) {
      int s = r2 * 256 + t;
      int row = s >> 2, slot = s & 3;
      int sw = (row ^ (row >> 2)) & 3;
      uint4 va = *(const uint4*)(xT + ((size_t)(b * NPIX + n0 + row)) * NC + kc * 32 + slot * 8);
      *(uint4*)((char*)At + row * 64 + ((slot ^ sw) * 16)) = va;
      uint4 vb = *(const uint4*)(Whbf + (size_t)(o0 + row) * NC + kc * 32 + slot * 8);
      *(uint4*)((char*)Bt + row * 64 + ((slot ^ sw) * 16)) = vb;
    }
    __syncthreads();
    bfv8 af[4], bfr[4];
#pragma unroll
    for (int mi = 0; mi < 4; mi++) {
      int row = wr * 64 + mi * 16 + coll;
      int slot = cg ^ ((row ^ (row >> 2)) & 3);
      af[mi] = *(const bfv8*)((const char*)At + row * 64 + slot * 16);
    }
#pragma unroll
    for (int ni = 0; ni < 4; ni++) {
      int row = wc * 64 + ni * 16 + coll;
      int slot = cg ^ ((row ^ (row >> 2)) & 3);
      bfr[ni] = *(const bfv8*)((const char*)Bt + row * 64 + slot * 16);
    }
#pragma unroll
    for (int mi = 0; mi < 4; mi++)
#pragma unroll
      for (int ni = 0; ni < 4; ni++)
        acc[mi][ni] = __builtin_amdgcn_mfma_f32_16x16x32_bf16(af[mi], bfr[ni], acc[mi][ni], 0, 0, 0);
  }
#pragma unroll
  for (int ni = 0; ni < 4; ni++) {
    int o = o0 + wc * 64 + ni * 16 + coll;
    float bias = bh[o];
#pragma unroll
    for (int mi = 0; mi < 4; mi++) {
      int px = n0 + wr * 64 + mi * 16 + cg * 4;
      u32 lo = cvtpk(acc[mi][ni][0] + bias, acc[mi][ni][1] + bias);
      u32 hi = cvtpk(acc[mi][ni][2] + bias, acc[mi][ni][3] + bias);
      *(uint2*)(h + ((size_t)(b * NC + o)) * NPIX + px) = make_uint2(lo, hi);
    }
  }
}

// ---------------- K5: pass 1 partials — per (b, j-tile, i-slice): m,d ----------------
__global__ __launch_bounds__(256) void k_pass1(const u16* __restrict__ fT,
                                               const u16* __restrict__ gT,
                                               float2* __restrict__ pmd) {
  __shared__ u16 gs[64 * 64];
  int blk = blockIdx.x;
  int iq = blk & 7, jt = (blk >> 3) & 63, b = blk >> 9;
  int j0 = jt * 64, ibase = iq * 512;
  int t = threadIdx.x, lane = t & 63, w = t >> 6;
  int coll = lane & 15, cg = lane >> 4;
  const u16* fr = fT + ((size_t)(b * NPIX) + j0 + w * 16 + coll) * 64 + cg * 8;
  bfv8 ah = *(const bfv8*)fr;
  bfv8 al = *(const bfv8*)(fr + 32);
  float m[4] = {-3e38f, -3e38f, -3e38f, -3e38f}, d[4] = {0.f, 0.f, 0.f, 0.f};
  int r0 = t >> 3, s0 = t & 7;
  uint4 v0 = *(const uint4*)(gT + ((size_t)(b * NPIX) + ibase + r0) * 64 + s0 * 8);
  uint4 v1 = *(const uint4*)(gT + ((size_t)(b * NPIX) + ibase + 32 + r0) * 64 + s0 * 8);
  for (int it2 = 0; it2 < 8; ++it2) {
    __syncthreads();
    *(uint4*)(&gs[r0 * 64 + ((s0 ^ (r0 & 7)) << 3)]) = v0;
    *(uint4*)(&gs[(32 + r0) * 64 + ((s0 ^ (r0 & 7)) << 3)]) = v1;
    __syncthreads();
    if (it2 < 7) {
      v0 = *(const uint4*)(gT + ((size_t)(b * NPIX) + ibase + (it2 + 1) * 64 + r0) * 64 + s0 * 8);
      v1 = *(const uint4*)(gT + ((size_t)(b * NPIX) + ibase + (it2 + 1) * 64 + 32 + r0) * 64 + s0 * 8);
    }
    float sv[4][4];
#pragma unroll
    for (int t4 = 0; t4 < 4; ++t4) {
      int row = t4 * 16 + coll;
      const u16* base = &gs[row * 64];
      bfv8 bh = *(const bfv8*)(base + ((cg ^ (row & 7)) << 3));
      bfv8 bl = *(const bfv8*)(base + (((4 + cg) ^ (row & 7)) << 3));
      f32x4 s = {0.f, 0.f, 0.f, 0.f};
      s = __builtin_amdgcn_mfma_f32_16x16x32_bf16(al, bh, s, 0, 0, 0);
      s = __builtin_amdgcn_mfma_f32_16x16x32_bf16(ah, bl, s, 0, 0, 0);
      s = __builtin_amdgcn_mfma_f32_16x16x32_bf16(ah, bh, s, 0, 0, 0);
      sv[t4][0] = s[0]; sv[t4][1] = s[1]; sv[t4][2] = s[2]; sv[t4][3] = s[3];
    }
#pragma unroll
    for (int r = 0; r < 4; ++r) {
      float ms = fmaxf(fmaxf(sv[0][r], sv[1][r]), fmaxf(sv[2][r], sv[3][r]));
      float nm = fmaxf(m[r], ms);
      d[r] = d[r] * __expf(m[r] - nm) + __expf(sv[0][r] - nm) + __expf(sv[1][r] - nm) +
             __expf(sv[2][r] - nm) + __expf(sv[3][r] - nm);
      m[r] = nm;
    }
  }
#pragma unroll
  for (int r = 0; r < 4; ++r) {
#pragma unroll
    for (int off = 1; off < 16; off <<= 1) {
      float m2 = __shfl_xor(m[r], off);
      float d2 = __shfl_xor(d[r], off);
      float nm = fmaxf(m[r], m2);
      d[r] = d[r] * __expf(m[r] - nm) + d2 * __expf(m2 - nm);
      m[r] = nm;
    }
  }
  if (coll == 0) {
#pragma unroll
    for (int r = 0; r < 4; ++r) {
      int j = j0 + w * 16 + cg * 4 + r;
      pmd[((size_t)(b * 8 + iq)) * NPIX + j] = make_float2(m[r], d[r]);
    }
  }
}

// ---------------- K5b: combine partials -> a_j = M*log2e + log2(D) ----------------
__global__ __launch_bounds__(256) void k_comb(const float2* __restrict__ pmd,
                                              float* __restrict__ aout) {
  int idx = blockIdx.x * 256 + threadIdx.x;  // 16384
  int b = idx >> 12, j = idx & 4095;
  float2 p[8];
  float M = -3e38f;
#pragma unroll
  for (int q = 0; q < 8; ++q) {
    p[q] = pmd[((size_t)(b * 8 + q)) * NPIX + j];
    M = fmaxf(M, p[q].x);
  }
  float D = 0.f;
#pragma unroll
  for (int q = 0; q < 8; ++q) D += p[q].y * __expf(p[q].x - M);
  aout[idx] = fmaf(M, LOG2E, __log2f(D));
}

// ---------------- K6: pass 2 partial — Opart[jq][b,c,i] (bf16), all 256 c ----------------
__global__ __launch_bounds__(256, 3) void k_pass2(const u16* __restrict__ fT,
                                                  const u16* __restrict__ gT,
                                                  const u16* __restrict__ h,
                                                  const float* __restrict__ arow,
                                                  u16* __restrict__ Opart) {
  __shared__ char smem[41216];
  u16* vt = (u16*)smem;                  // [256 c][64 j] swizzled, 32KB
  u16* pl = (u16*)(smem + 32768);        // [4 w][16 i][64 j] swizzled, 8KB
  float* alds = (float*)(smem + 40960);  // [64 j]
  float* tb = (float*)smem;              // epilogue alias (64*65*4 = 16.6KB)
  int blk = blockIdx.x;
  int jq = blk & 1, it = (blk >> 1) & 63, b = blk >> 7;
  int i0 = it * 64, jbase = jq * 2048;
  int t = threadIdx.x, lane = t & 63, w = t >> 6;
  int coll = lane & 15, cg = lane >> 4;
  // g B-frags for this wave's i-subtile (fixed)
  const u16* gr = gT + ((size_t)(b * NPIX) + i0 + w * 16 + coll) * 64 + cg * 8;
  bfv8 gh = *(const bfv8*)gr;
  bfv8 gl = *(const bfv8*)(gr + 32);
  f32x4 acc[16] = {};
  uint4 hv[8];
  float apre = 0.f;
  int hrow = t >> 3, hslot = t & 7;
#pragma unroll
  for (int q = 0; q < 8; ++q) {
    int row = q * 32 + hrow;
    hv[q] = *(const uint4*)(h + ((size_t)(b * NC) + row) * NPIX + jbase + hslot * 8);
  }
  if (t < 64) apre = arow[b * NPIX + jbase + t];
  // f A-frags, loop-carried (shared j-rows across waves)
  bfv8 fh[4], fl[4];
#pragma unroll
  for (int jt2 = 0; jt2 < 4; ++jt2) {
    const u16* fr2 = fT + ((size_t)(b * NPIX) + jbase + jt2 * 16 + coll) * 64 + cg * 8;
    fh[jt2] = *(const bfv8*)fr2;
    fl[jt2] = *(const bfv8*)(fr2 + 32);
  }
  for (int jc = 0; jc < 32; ++jc) {
    int j1 = jbase + (jc + 1) * 64;
    __syncthreads();
#pragma unroll
    for (int q = 0; q < 8; ++q) {
      int row = q * 32 + hrow;
      *(uint4*)(&vt[row * 64 + ((hslot ^ (row & 7)) << 3)]) = hv[q];
    }
    if (t < 64) alds[t] = apre;
    __syncthreads();
    if (jc < 31) {
#pragma unroll
      for (int q = 0; q < 8; ++q) {
        int row = q * 32 + hrow;
        hv[q] = *(const uint4*)(h + ((size_t)(b * NC) + row) * NPIX + j1 + hslot * 8);
      }
      if (t < 64) apre = arow[b * NPIX + j1 + t];
    }
    // QK per j-subtile: 3 MFMA -> reload frags for next iter -> exp2 -> P^T to LDS
#pragma unroll
    for (int jt2 = 0; jt2 < 4; ++jt2) {
      f32x4 s = {0.f, 0.f, 0.f, 0.f};
      s = __builtin_amdgcn_mfma_f32_16x16x32_bf16(fl[jt2], gh, s, 0, 0, 0);
      s = __builtin_amdgcn_mfma_f32_16x16x32_bf16(fh[jt2], gl, s, 0, 0, 0);
      s = __builtin_amdgcn_mfma_f32_16x16x32_bf16(fh[jt2], gh, s, 0, 0, 0);
      if (jc < 31) {
        const u16* fr2 = fT + ((size_t)(b * NPIX) + j1 + jt2 * 16 + coll) * 64 + cg * 8;
        fh[jt2] = *(const bfv8*)fr2;
        fl[jt2] = *(const bfv8*)(fr2 + 32);
      }
      int jr = jt2 * 16 + cg * 4;
      float4 av = *(const float4*)&alds[jr];
      float p0 = exp2f(fmaf(s[0], LOG2E, -av.x));
      float p1 = exp2f(fmaf(s[1], LOG2E, -av.y));
      float p2 = exp2f(fmaf(s[2], LOG2E, -av.z));
      float p3 = exp2f(fmaf(s[3], LOG2E, -av.w));
      char* pb = (char*)pl + w * 2048 + coll * 128;
      *(uint2*)(pb + ((jt2 * 32 + cg * 8) ^ ((coll & 7) << 4))) =
          make_uint2(cvtpk(p0, p1), cvtpk(p2, p3));
    }
    // PV over all 256 channels
    bfv8 pa[2];
#pragma unroll
    for (int kb = 0; kb < 2; ++kb) {
      const char* pb = (const char*)pl + w * 2048 + coll * 128;
      pa[kb] = *(const bfv8*)(pb + ((kb * 64 + cg * 16) ^ ((coll & 7) << 4)));
    }
#pragma unroll
    for (int ct = 0; ct < 16; ++ct) {
      int row = ct * 16 + coll;
      const char* vb = (const char*)vt + row * 128;
      int sw = (row & 7) << 4;
#pragma unroll
      for (int kb = 0; kb < 2; ++kb) {
        bfv8 bv = *(const bfv8*)(vb + ((kb * 64 + cg * 16) ^ sw));
        acc[ct] = __builtin_amdgcn_mfma_f32_16x16x32_bf16(pa[kb], bv, acc[ct], 0, 0, 0);
      }
    }
  }
  // epilogue: transpose in LDS, write bf16 partials
  for (int ch = 0; ch < 4; ++ch) {
    __syncthreads();
#pragma unroll
    for (int q2 = 0; q2 < 4; ++q2)
#pragma unroll
      for (int rr = 0; rr < 4; ++rr)
        tb[(w * 16 + cg * 4 + rr) * 65 + q2 * 16 + coll] = acc[ch * 4 + q2][rr];
    __syncthreads();
    int crow = t >> 2, part = t & 3;
    u16* op = Opart + (size_t)jq * TOT +
              ((size_t)(b * NC) + ch * 64 + crow) * NPIX + i0 + part * 16;
#pragma unroll
    for (int v = 0; v < 4; ++v) {
      float s0 = tb[(part * 16 + v * 4 + 0) * 65 + crow];
      float s1 = tb[(part * 16 + v * 4 + 1) * 65 + crow];
      float s2 = tb[(part * 16 + v * 4 + 2) * 65 + crow];
      float s3 = tb[(part * 16 + v * 4 + 3) * 65 + crow];
      *(uint2*)(op + v * 4) = make_uint2(cvtpk(s0, s1), cvtpk(s2, s3));
    }
  }
}

// ---------------- K7: reduce partials + residual ----------------
__global__ __launch_bounds__(256) void k_reduce(const u16* __restrict__ Opart,
                                                const float* __restrict__ x,
                                                const float* __restrict__ gamma,
                                                float* __restrict__ out) {
  int i = (blockIdx.x * 256 + threadIdx.x) * 4;
  uint2 a = *(const uint2*)(Opart + i);
  uint2 c = *(const uint2*)(Opart + TOT + i);
  float4 xv = *(const float4*)(x + i);
  float gam = gamma[0];
  float4 ov;
  ov.x = gam * (bf2f((u16)(a.x & 0xffff)) + bf2f((u16)(c.x & 0xffff))) + xv.x;
  ov.y = gam * (bf2f((u16)(a.x >> 16)) + bf2f((u16)(c.x >> 16))) + xv.y;
  ov.z = gam * (bf2f((u16)(a.y & 0xffff)) + bf2f((u16)(c.y & 0xffff))) + xv.z;
  ov.w = gam * (bf2f((u16)(a.y >> 16)) + bf2f((u16)(c.y >> 16))) + xv.w;
  *(float4*)(out + i) = ov;
}

extern "C" void kernel_launch(void* const* d_in, const int* in_sizes, int n_in,
                              void* d_out, int out_size, void* d_ws, size_t ws_size,
                              hipStream_t stream) {
  (void)in_sizes; (void)n_in; (void)out_size; (void)ws_size;
  const float* x = (const float*)d_in[0];
  const float* Wf = (const float*)d_in[1];
  const float* bf_ = (const float*)d_in[2];
  const float* Wg = (const float*)d_in[3];
  const float* bg_ = (const float*)d_in[4];
  const float* Wh = (const float*)d_in[5];
  const float* bh = (const float*)d_in[6];
  const float* gamma = (const float*)d_in[7];
  float* out = (float*)d_out;
  char* ws = (char*)d_ws;
  const size_t M1 = 1u << 20;
  // [0, 16M): xT (first 8MB; dead after k_h) then reused as Opart (2x bf16 partials)
  u16* xT = (u16*)ws;
  u16* Opart = (u16*)ws;
  u16* h = (u16*)(ws + 17 * M1);
  u16* fT = (u16*)(ws + 25 * M1);
  u16* gT = (u16*)(ws + 27 * M1);
  float* aout = (float*)(ws + 29 * M1);                        // 64KB
  float2* pmd = (float2*)(ws + 29 * M1 + (1u << 17));          // 1MB
  u16* Whbf = (u16*)(ws + 29 * M1 + (1u << 17) + (1u << 20));  // 128KB

  k_convert_wh<<<64, 256, 0, stream>>>(Wh, Whbf);
  k_transpose<<<1024, 256, 0, stream>>>(x, xT);
  k_fg<<<256, 256, 0, stream>>>(x, Wf, bf_, Wg, bg_, fT, gT);
  k_h<<<256, 256, 0, stream>>>(xT, Whbf, bh, h);
  k_pass1<<<2048, 256, 0, stream>>>(fT, gT, pmd);
  k_comb<<<64, 256, 0, stream>>>(pmd, aout);
  k_pass2<<<512, 256, 0, stream>>>(fT, gT, h, aout, Opart);
  k_reduce<<<4096, 256, 0, stream>>>(Opart, x, gamma, out);
}

// Round 5
// 196.658 us; speedup vs baseline: 1.5943x; 1.5108x over previous
//
#include <hip/hip_runtime.h>

#define NB 4
#define NC 256
#define NCK 32
#define NPIX 4096
#define TOT (NB * NC * NPIX)

typedef unsigned short u16;
typedef unsigned int u32;
typedef __bf16 bfv8 __attribute__((ext_vector_type(8)));
typedef float f32x4 __attribute__((ext_vector_type(4)));
#define LOG2E 1.4426950408889634f

__device__ inline u16 f2bf(float f) {
  union { float f; u32 u; } v; v.f = f;
  u32 r = v.u + 0x7fffu + ((v.u >> 16) & 1u);  // RNE
  return (u16)(r >> 16);
}
__device__ inline float bf2f(u16 h) {
  union { u32 u; float f; } v; v.u = (u32)h << 16; return v.f;
}
__device__ inline u32 cvtpk(float a, float b) {
  u32 r;
  asm("v_cvt_pk_bf16_f32 %0, %1, %2" : "=v"(r) : "v"(a), "v"(b));
  return r;
}

// ---------------- K1: convert Wh (fp32 256x256) -> bf16 ----------------
__global__ __launch_bounds__(256) void k_convert_wh(const float* __restrict__ Wh,
                                                    u16* __restrict__ Whbf) {
  int i = (blockIdx.x * 256 + threadIdx.x) * 4;
  float4 v = *(const float4*)(Wh + i);
  *(uint2*)(Whbf + i) = make_uint2(cvtpk(v.x, v.y), cvtpk(v.z, v.w));
}

// ---------------- K3: f,g projections + xT emit ----------------
// fT[b][n][0:32]=hi, [32:64]=lo ; gT likewise; xT[b][n][c] bf16
__global__ __launch_bounds__(256) void k_fg(const float* __restrict__ x,
                                            const float* __restrict__ Wf,
                                            const float* __restrict__ bf_,
                                            const float* __restrict__ Wg,
                                            const float* __restrict__ bg_,
                                            u16* __restrict__ fT,
                                            u16* __restrict__ gT,
                                            u16* __restrict__ xT) {
  __shared__ float Wt[256][65];
  __shared__ float xl[32][68];
  __shared__ float tb[64][68];
  int blk = blockIdx.x;
  int b = blk >> 6;
  int n0 = (blk & 63) * 64;
  int t = threadIdx.x;
  int tx = t & 15, ty = t >> 4;
  for (int r = 0; r < 64; r++) {
    float w = (r < 32) ? Wf[r * 256 + t] : Wg[(r - 32) * 256 + t];
    Wt[t][r] = w;
  }
  float acc[4][4] = {};
  int n = t >> 2, cp = t & 3;
  for (int kc = 0; kc < 8; kc++) {
    __syncthreads();
#pragma unroll
    for (int r = 0; r < 2; r++) {
      int e = (r * 256 + t) * 4;
      int row = e >> 6, col = e & 63;
      *(float4*)&xl[row][col] =
          *(const float4*)(x + ((size_t)(b * NC + kc * 32 + row)) * NPIX + n0 + col);
    }
    __syncthreads();
    // emit xT slice [64 n][32 c] bf16
    {
      u32 uu[4];
#pragma unroll
      for (int q = 0; q < 4; q++)
        uu[q] = cvtpk(xl[cp * 8 + 2 * q][n], xl[cp * 8 + 2 * q + 1][n]);
      *(uint4*)(xT + ((size_t)(b * NPIX) + n0 + n) * NC + kc * 32 + cp * 8) =
          make_uint4(uu[0], uu[1], uu[2], uu[3]);
    }
#pragma unroll
    for (int kk = 0; kk < 32; kk++) {
      float4 xv = *(const float4*)&xl[kk][tx * 4];
      float w0 = Wt[kc * 32 + kk][ty * 4 + 0];
      float w1 = Wt[kc * 32 + kk][ty * 4 + 1];
      float w2 = Wt[kc * 32 + kk][ty * 4 + 2];
      float w3 = Wt[kc * 32 + kk][ty * 4 + 3];
      acc[0][0] += w0 * xv.x; acc[0][1] += w0 * xv.y; acc[0][2] += w0 * xv.z; acc[0][3] += w0 * xv.w;
      acc[1][0] += w1 * xv.x; acc[1][1] += w1 * xv.y; acc[1][2] += w1 * xv.z; acc[1][3] += w1 * xv.w;
      acc[2][0] += w2 * xv.x; acc[2][1] += w2 * xv.y; acc[2][2] += w2 * xv.z; acc[2][3] += w2 * xv.w;
      acc[3][0] += w3 * xv.x; acc[3][1] += w3 * xv.y; acc[3][2] += w3 * xv.z; acc[3][3] += w3 * xv.w;
    }
  }
#pragma unroll
  for (int j = 0; j < 4; j++) {
    int o = ty * 4 + j;
    float bias = (o < 32) ? bf_[o] : bg_[o - 32];
#pragma unroll
    for (int vi = 0; vi < 4; vi++) tb[tx * 4 + vi][o] = acc[j][vi] + bias;
  }
  __syncthreads();
  int part = t & 3;
  {
    u32 ph[4], plo[4];
#pragma unroll
    for (int e = 0; e < 4; e++) {
      float v0 = tb[n][part * 8 + 2 * e + 0];
      float v1 = tb[n][part * 8 + 2 * e + 1];
      u16 h0 = f2bf(v0), h1 = f2bf(v1);
      u16 l0 = f2bf(v0 - bf2f(h0)), l1 = f2bf(v1 - bf2f(h1));
      ph[e] = (u32)h0 | ((u32)h1 << 16);
      plo[e] = (u32)l0 | ((u32)l1 << 16);
    }
    u16* dst = fT + ((size_t)(b * NPIX) + n0 + n) * 64 + part * 8;
    *(uint4*)dst = make_uint4(ph[0], ph[1], ph[2], ph[3]);
    *(uint4*)(dst + 32) = make_uint4(plo[0], plo[1], plo[2], plo[3]);
  }
  {
    u32 ph[4], plo[4];
#pragma unroll
    for (int e = 0; e < 4; e++) {
      float v0 = tb[n][32 + part * 8 + 2 * e + 0];
      float v1 = tb[n][32 + part * 8 + 2 * e + 1];
      u16 h0 = f2bf(v0), h1 = f2bf(v1);
      u16 l0 = f2bf(v0 - bf2f(h0)), l1 = f2bf(v1 - bf2f(h1));
      ph[e] = (u32)h0 | ((u32)h1 << 16);
      plo[e] = (u32)l0 | ((u32)l1 << 16);
    }
    u16* dst = gT + ((size_t)(b * NPIX) + n0 + n) * 64 + part * 8;
    *(uint4*)dst = make_uint4(ph[0], ph[1], ph[2], ph[3]);
    *(uint4*)(dst + 32) = make_uint4(plo[0], plo[1], plo[2], plo[3]);
  }
}

// ---------------- K4: h projection (bf16 MFMA GEMM) ----------------
__global__ __launch_bounds__(256) void k_h(const u16* __restrict__ xT,
                                           const u16* __restrict__ Whbf,
                                           const float* __restrict__ bh,
                                           u16* __restrict__ h) {
  __shared__ u16 At[128 * 32];
  __shared__ u16 Bt[128 * 32];
  int blk = blockIdx.x;
  int b = blk >> 6, r = blk & 63;
  int nt = r >> 1, ot = r & 1;
  int n0 = nt * 128, o0 = ot * 128;
  int t = threadIdx.x, lane = t & 63, w = t >> 6;
  int wr = w >> 1, wc = w & 1;
  int coll = lane & 15, cg = lane >> 4;
  f32x4 acc[4][4] = {};
  for (int kc = 0; kc < 8; kc++) {
    __syncthreads();
#pragma unroll
    for (int r2 = 0; r2 < 2; r2++) {
      int s = r2 * 256 + t;
      int row = s >> 2, slot = s & 3;
      int sw = (row ^ (row >> 2)) & 3;
      uint4 va = *(const uint4*)(xT + ((size_t)(b * NPIX + n0 + row)) * NC + kc * 32 + slot * 8);
      *(uint4*)((char*)At + row * 64 + ((slot ^ sw) * 16)) = va;
      uint4 vb = *(const uint4*)(Whbf + (size_t)(o0 + row) * NC + kc * 32 + slot * 8);
      *(uint4*)((char*)Bt + row * 64 + ((slot ^ sw) * 16)) = vb;
    }
    __syncthreads();
    bfv8 af[4], bfr[4];
#pragma unroll
    for (int mi = 0; mi < 4; mi++) {
      int row = wr * 64 + mi * 16 + coll;
      int slot = cg ^ ((row ^ (row >> 2)) & 3);
      af[mi] = *(const bfv8*)((const char*)At + row * 64 + slot * 16);
    }
#pragma unroll
    for (int ni = 0; ni < 4; ni++) {
      int row = wc * 64 + ni * 16 + coll;
      int slot = cg ^ ((row ^ (row >> 2)) & 3);
      bfr[ni] = *(const bfv8*)((const char*)Bt + row * 64 + slot * 16);
    }
#pragma unroll
    for (int mi = 0; mi < 4; mi++)
#pragma unroll
      for (int ni = 0; ni < 4; ni++)
        acc[mi][ni] = __builtin_amdgcn_mfma_f32_16x16x32_bf16(af[mi], bfr[ni], acc[mi][ni], 0, 0, 0);
  }
#pragma unroll
  for (int ni = 0; ni < 4; ni++) {
    int o = o0 + wc * 64 + ni * 16 + coll;
    float bias = bh[o];
#pragma unroll
    for (int mi = 0; mi < 4; mi++) {
      int px = n0 + wr * 64 + mi * 16 + cg * 4;
      u32 lo = cvtpk(acc[mi][ni][0] + bias, acc[mi][ni][1] + bias);
      u32 hi = cvtpk(acc[mi][ni][2] + bias, acc[mi][ni][3] + bias);
      *(uint2*)(h + ((size_t)(b * NC + o)) * NPIX + px) = make_uint2(lo, hi);
    }
  }
}

// ---------------- K5: pass 1 partials — per (b, j-tile, i-slice): m,d ----------------
__global__ __launch_bounds__(256) void k_pass1(const u16* __restrict__ fT,
                                               const u16* __restrict__ gT,
                                               float2* __restrict__ pmd) {
  __shared__ u16 gs[64 * 64];
  int blk = blockIdx.x;
  int iq = blk & 7, jt = (blk >> 3) & 63, b = blk >> 9;
  int j0 = jt * 64, ibase = iq * 512;
  int t = threadIdx.x, lane = t & 63, w = t >> 6;
  int coll = lane & 15, cg = lane >> 4;
  const u16* fr = fT + ((size_t)(b * NPIX) + j0 + w * 16 + coll) * 64 + cg * 8;
  bfv8 ah = *(const bfv8*)fr;
  bfv8 al = *(const bfv8*)(fr + 32);
  float m[4] = {-3e38f, -3e38f, -3e38f, -3e38f}, d[4] = {0.f, 0.f, 0.f, 0.f};
  int r0 = t >> 3, s0 = t & 7;
  uint4 v0 = *(const uint4*)(gT + ((size_t)(b * NPIX) + ibase + r0) * 64 + s0 * 8);
  uint4 v1 = *(const uint4*)(gT + ((size_t)(b * NPIX) + ibase + 32 + r0) * 64 + s0 * 8);
  for (int it2 = 0; it2 < 8; ++it2) {
    __syncthreads();
    *(uint4*)(&gs[r0 * 64 + ((s0 ^ (r0 & 7)) << 3)]) = v0;
    *(uint4*)(&gs[(32 + r0) * 64 + ((s0 ^ (r0 & 7)) << 3)]) = v1;
    __syncthreads();
    if (it2 < 7) {
      v0 = *(const uint4*)(gT + ((size_t)(b * NPIX) + ibase + (it2 + 1) * 64 + r0) * 64 + s0 * 8);
      v1 = *(const uint4*)(gT + ((size_t)(b * NPIX) + ibase + (it2 + 1) * 64 + 32 + r0) * 64 + s0 * 8);
    }
    float sv[4][4];
#pragma unroll
    for (int t4 = 0; t4 < 4; ++t4) {
      int row = t4 * 16 + coll;
      const u16* base = &gs[row * 64];
      bfv8 bh = *(const bfv8*)(base + ((cg ^ (row & 7)) << 3));
      bfv8 bl = *(const bfv8*)(base + (((4 + cg) ^ (row & 7)) << 3));
      f32x4 s = {0.f, 0.f, 0.f, 0.f};
      s = __builtin_amdgcn_mfma_f32_16x16x32_bf16(al, bh, s, 0, 0, 0);
      s = __builtin_amdgcn_mfma_f32_16x16x32_bf16(ah, bl, s, 0, 0, 0);
      s = __builtin_amdgcn_mfma_f32_16x16x32_bf16(ah, bh, s, 0, 0, 0);
      sv[t4][0] = s[0]; sv[t4][1] = s[1]; sv[t4][2] = s[2]; sv[t4][3] = s[3];
    }
#pragma unroll
    for (int r = 0; r < 4; ++r) {
      float ms = fmaxf(fmaxf(sv[0][r], sv[1][r]), fmaxf(sv[2][r], sv[3][r]));
      float nm = fmaxf(m[r], ms);
      d[r] = d[r] * __expf(m[r] - nm) + __expf(sv[0][r] - nm) + __expf(sv[1][r] - nm) +
             __expf(sv[2][r] - nm) + __expf(sv[3][r] - nm);
      m[r] = nm;
    }
  }
#pragma unroll
  for (int r = 0; r < 4; ++r) {
#pragma unroll
    for (int off = 1; off < 16; off <<= 1) {
      float m2 = __shfl_xor(m[r], off);
      float d2 = __shfl_xor(d[r], off);
      float nm = fmaxf(m[r], m2);
      d[r] = d[r] * __expf(m[r] - nm) + d2 * __expf(m2 - nm);
      m[r] = nm;
    }
  }
  if (coll == 0) {
#pragma unroll
    for (int r = 0; r < 4; ++r) {
      int j = j0 + w * 16 + cg * 4 + r;
      pmd[((size_t)(b * 8 + iq)) * NPIX + j] = make_float2(m[r], d[r]);
    }
  }
}

// ---------------- K5b: combine partials -> a_j = M*log2e + log2(D) ----------------
__global__ __launch_bounds__(256) void k_comb(const float2* __restrict__ pmd,
                                              float* __restrict__ aout) {
  int idx = blockIdx.x * 256 + threadIdx.x;  // 16384
  int b = idx >> 12, j = idx & 4095;
  float2 p[8];
  float M = -3e38f;
#pragma unroll
  for (int q = 0; q < 8; ++q) {
    p[q] = pmd[((size_t)(b * 8 + q)) * NPIX + j];
    M = fmaxf(M, p[q].x);
  }
  float D = 0.f;
#pragma unroll
  for (int q = 0; q < 8; ++q) D += p[q].y * __expf(p[q].x - M);
  aout[idx] = fmaf(M, LOG2E, __log2f(D));
}

// ---------------- K6: pass 2 — Opart[jq][b,c,i] (bf16), h in registers ----------------
__global__ __launch_bounds__(256, 2) void k_pass2(const u16* __restrict__ fT,
                                                  const u16* __restrict__ gT,
                                                  const u16* __restrict__ h,
                                                  const float* __restrict__ arow,
                                                  u16* __restrict__ Opart) {
  // pl[2][4 waves][2KB] = 16KB; alds[2][64] floats at 16384; epilogue tbf alias 64x68 f32
  __shared__ char smem[17408];
  int blk = blockIdx.x;
  int jq = blk & 1, it = (blk >> 1) & 63, b = blk >> 7;
  int i0 = it * 64, jbase = jq * 2048;
  int t = threadIdx.x, lane = t & 63, w = t >> 6;
  int coll = lane & 15, cg = lane >> 4;
  int cbase = w * 64;
  int swz = (coll & 7) << 4;
  // g B-frags (fixed): wave's i-subtile
  const u16* gr = gT + ((size_t)(b * NPIX) + i0 + w * 16 + coll) * 64 + cg * 8;
  bfv8 gh = *(const bfv8*)gr;
  bfv8 gl = *(const bfv8*)(gr + 32);
  f32x4 acc[4][4] = {};  // [ct (c-sub)][ni (i-sub)]
  // h A-frags for this wave's 64-channel slice, register-resident
  const u16* hbase = h + ((size_t)(b * NC) + cbase + coll) * NPIX + jbase + cg * 8;
  bfv8 hv[4][2];
#pragma unroll
  for (int ct = 0; ct < 4; ++ct)
#pragma unroll
    for (int kb = 0; kb < 2; ++kb)
      hv[ct][kb] = *(const bfv8*)(hbase + (size_t)(ct * 16) * NPIX + kb * 32);
  // f A-frags for QK (shared across waves)
  bfv8 fh[4], fl[4];
#pragma unroll
  for (int jt2 = 0; jt2 < 4; ++jt2) {
    const u16* fr2 = fT + ((size_t)(b * NPIX) + jbase + jt2 * 16 + coll) * 64 + cg * 8;
    fh[jt2] = *(const bfv8*)fr2;
    fl[jt2] = *(const bfv8*)(fr2 + 32);
  }
  float apre = 0.f;
  if (t < 64) ((float*)(smem + 16384))[t] = arow[b * NPIX + jbase + t];
  // QK(0)
  f32x4 s[4];
#pragma unroll
  for (int jt2 = 0; jt2 < 4; ++jt2) {
    f32x4 ss = {0.f, 0.f, 0.f, 0.f};
    ss = __builtin_amdgcn_mfma_f32_16x16x32_bf16(fl[jt2], gh, ss, 0, 0, 0);
    ss = __builtin_amdgcn_mfma_f32_16x16x32_bf16(fh[jt2], gl, ss, 0, 0, 0);
    ss = __builtin_amdgcn_mfma_f32_16x16x32_bf16(fh[jt2], gh, ss, 0, 0, 0);
    s[jt2] = ss;
  }
  // f(1), a(1)
#pragma unroll
  for (int jt2 = 0; jt2 < 4; ++jt2) {
    const u16* fr2 = fT + ((size_t)(b * NPIX) + jbase + 64 + jt2 * 16 + coll) * 64 + cg * 8;
    fh[jt2] = *(const bfv8*)fr2;
    fl[jt2] = *(const bfv8*)(fr2 + 32);
  }
  if (t < 64) apre = arow[b * NPIX + jbase + 64 + t];
  __syncthreads();

  for (int jc = 0; jc < 32; ++jc) {
    int p = jc & 1;
    // ---- exp + P write (pre-barrier phase) ----
    const float* alds = (const float*)(smem + 16384) + p * 64;
#pragma unroll
    for (int jt2 = 0; jt2 < 4; ++jt2) {
      int jr = jt2 * 16 + cg * 4;
      float4 av = *(const float4*)&alds[jr];
      float p0 = exp2f(fmaf(s[jt2][0], LOG2E, -av.x));
      float p1 = exp2f(fmaf(s[jt2][1], LOG2E, -av.y));
      float p2 = exp2f(fmaf(s[jt2][2], LOG2E, -av.z));
      float p3 = exp2f(fmaf(s[jt2][3], LOG2E, -av.w));
      char* pb = smem + p * 8192 + w * 2048 + coll * 128;
      *(uint2*)(pb + ((jt2 * 32 + cg * 8) ^ swz)) =
          make_uint2(cvtpk(p0, p1), cvtpk(p2, p3));
    }
    if (t < 64) ((float*)(smem + 16384))[((jc + 1) & 1) * 64 + t] = apre;
    __syncthreads();
    // ---- PV phase ----
#pragma unroll
    for (int ni = 0; ni < 4; ++ni) {
      const char* pbr = smem + p * 8192 + ni * 2048 + coll * 128;
      bfv8 pa0 = *(const bfv8*)(pbr + ((cg * 16) ^ swz));
      bfv8 pa1 = *(const bfv8*)(pbr + ((64 + cg * 16) ^ swz));
#pragma unroll
      for (int ct = 0; ct < 4; ++ct) {
        acc[ct][ni] = __builtin_amdgcn_mfma_f32_16x16x32_bf16(hv[ct][0], pa0, acc[ct][ni], 0, 0, 0);
        acc[ct][ni] = __builtin_amdgcn_mfma_f32_16x16x32_bf16(hv[ct][1], pa1, acc[ct][ni], 0, 0, 0);
      }
    }
    if (jc < 31) {
      // next h frags (consumed next PV; latency covered by QK+exp+barrier)
      const u16* hb2 = hbase + (jc + 1) * 64;
#pragma unroll
      for (int ct = 0; ct < 4; ++ct)
#pragma unroll
        for (int kb = 0; kb < 2; ++kb)
          hv[ct][kb] = *(const bfv8*)(hb2 + (size_t)(ct * 16) * NPIX + kb * 32);
      // QK(jc+1) with f(jc+1)
#pragma unroll
      for (int jt2 = 0; jt2 < 4; ++jt2) {
        f32x4 ss = {0.f, 0.f, 0.f, 0.f};
        ss = __builtin_amdgcn_mfma_f32_16x16x32_bf16(fl[jt2], gh, ss, 0, 0, 0);
        ss = __builtin_amdgcn_mfma_f32_16x16x32_bf16(fh[jt2], gl, ss, 0, 0, 0);
        ss = __builtin_amdgcn_mfma_f32_16x16x32_bf16(fh[jt2], gh, ss, 0, 0, 0);
        s[jt2] = ss;
      }
      if (jc < 30) {
        // f(jc+2), a(jc+2)
#pragma unroll
        for (int jt2 = 0; jt2 < 4; ++jt2) {
          const u16* fr2 =
              fT + ((size_t)(b * NPIX) + jbase + (jc + 2) * 64 + jt2 * 16 + coll) * 64 + cg * 8;
          fh[jt2] = *(const bfv8*)fr2;
          fl[jt2] = *(const bfv8*)(fr2 + 32);
        }
        if (t < 64) apre = arow[b * NPIX + jbase + (jc + 2) * 64 + t];
      }
    }
  }
  // ---- epilogue: per-wave transpose via LDS, write bf16 partials ----
  int rr = lane >> 2, part = lane & 3;
  for (int rd = 0; rd < 4; ++rd) {
    __syncthreads();
    float* tbf = (float*)smem;
#pragma unroll
    for (int ni = 0; ni < 4; ++ni)
#pragma unroll
      for (int r = 0; r < 4; ++r)
        tbf[(w * 16 + cg * 4 + r) * 68 + ni * 16 + coll] = acc[rd][ni][r];
    __syncthreads();
    const float* src = &((float*)smem)[(w * 16 + rr) * 68 + part * 16];
    u32 uu[8];
#pragma unroll
    for (int q = 0; q < 8; ++q) uu[q] = cvtpk(src[2 * q], src[2 * q + 1]);
    u16* op = Opart + (size_t)jq * TOT +
              ((size_t)(b * NC) + cbase + rd * 16 + rr) * NPIX + i0 + part * 16;
    *(uint4*)op = make_uint4(uu[0], uu[1], uu[2], uu[3]);
    *(uint4*)(op + 8) = make_uint4(uu[4], uu[5], uu[6], uu[7]);
  }
}

// ---------------- K7: reduce partials + residual ----------------
__global__ __launch_bounds__(256) void k_reduce(const u16* __restrict__ Opart,
                                                const float* __restrict__ x,
                                                const float* __restrict__ gamma,
                                                float* __restrict__ out) {
  int i = (blockIdx.x * 256 + threadIdx.x) * 4;
  uint2 a = *(const uint2*)(Opart + i);
  uint2 c = *(const uint2*)(Opart + TOT + i);
  float4 xv = *(const float4*)(x + i);
  float gam = gamma[0];
  float4 ov;
  ov.x = gam * (bf2f((u16)(a.x & 0xffff)) + bf2f((u16)(c.x & 0xffff))) + xv.x;
  ov.y = gam * (bf2f((u16)(a.x >> 16)) + bf2f((u16)(c.x >> 16))) + xv.y;
  ov.z = gam * (bf2f((u16)(a.y & 0xffff)) + bf2f((u16)(c.y & 0xffff))) + xv.z;
  ov.w = gam * (bf2f((u16)(a.y >> 16)) + bf2f((u16)(c.y >> 16))) + xv.w;
  *(float4*)(out + i) = ov;
}

extern "C" void kernel_launch(void* const* d_in, const int* in_sizes, int n_in,
                              void* d_out, int out_size, void* d_ws, size_t ws_size,
                              hipStream_t stream) {
  (void)in_sizes; (void)n_in; (void)out_size; (void)ws_size;
  const float* x = (const float*)d_in[0];
  const float* Wf = (const float*)d_in[1];
  const float* bf_ = (const float*)d_in[2];
  const float* Wg = (const float*)d_in[3];
  const float* bg_ = (const float*)d_in[4];
  const float* Wh = (const float*)d_in[5];
  const float* bh = (const float*)d_in[6];
  const float* gamma = (const float*)d_in[7];
  float* out = (float*)d_out;
  char* ws = (char*)d_ws;
  const size_t M1 = 1u << 20;
  // [0,16M): xT (8MB, dead after k_h) then Opart (2 bf16 partials, 16MB)
  u16* xT = (u16*)ws;
  u16* Opart = (u16*)ws;
  u16* h = (u16*)(ws + 17 * M1);
  u16* fT = (u16*)(ws + 25 * M1);
  u16* gT = (u16*)(ws + 27 * M1);
  float* aout = (float*)(ws + 29 * M1);                        // 64KB
  float2* pmd = (float2*)(ws + 29 * M1 + (1u << 17));          // 1MB
  u16* Whbf = (u16*)(ws + 29 * M1 + (1u << 17) + (1u << 20));  // 128KB

  k_convert_wh<<<64, 256, 0, stream>>>(Wh, Whbf);
  k_fg<<<256, 256, 0, stream>>>(x, Wf, bf_, Wg, bg_, fT, gT, xT);
  k_pass1<<<2048, 256, 0, stream>>>(fT, gT, pmd);
  k_h<<<256, 256, 0, stream>>>(xT, Whbf, bh, h);
  k_comb<<<64, 256, 0, stream>>>(pmd, aout);
  k_pass2<<<512, 256, 0, stream>>>(fT, gT, h, aout, Opart);
  k_reduce<<<4096, 256, 0, stream>>>(Opart, x, gamma, out);
}

// Round 6
// 135.997 us; speedup vs baseline: 2.3055x; 1.4461x over previous
//
#include <hip/hip_runtime.h>

#define NB 4
#define NC 256
#define NCK 32
#define NPIX 4096
#define TOT (NB * NC * NPIX)

typedef unsigned short u16;
typedef unsigned int u32;
typedef __bf16 bfv8 __attribute__((ext_vector_type(8)));
typedef float f32x4 __attribute__((ext_vector_type(4)));
#define LOG2E 1.4426950408889634f

__device__ inline u16 f2bf(float f) {
  union { float f; u32 u; } v; v.f = f;
  u32 r = v.u + 0x7fffu + ((v.u >> 16) & 1u);  // RNE
  return (u16)(r >> 16);
}
__device__ inline float bf2f(u16 h) {
  union { u32 u; float f; } v; v.u = (u32)h << 16; return v.f;
}
__device__ inline u32 cvtpk(float a, float b) {
  u32 r;
  asm("v_cvt_pk_bf16_f32 %0, %1, %2" : "=v"(r) : "v"(a), "v"(b));
  return r;
}

// ---------------- K3: f,g projections + xT emit ----------------
// fP: fragment-tiled [b][jt=n/16][hi/lo][16 r][32 k] bf16 (1024 elems per jt)
// gT: flat [b][n][0:32 hi | 32:64 lo]
// xT: [b][n][c] bf16
__global__ __launch_bounds__(256) void k_fg(const float* __restrict__ x,
                                            const float* __restrict__ Wf,
                                            const float* __restrict__ bf_,
                                            const float* __restrict__ Wg,
                                            const float* __restrict__ bg_,
                                            u16* __restrict__ fP,
                                            u16* __restrict__ gT,
                                            u16* __restrict__ xT) {
  __shared__ float Wt[256][65];
  __shared__ float xl[32][68];
  __shared__ float tb[64][68];
  int blk = blockIdx.x;
  int b = blk >> 6;
  int n0 = (blk & 63) * 64;
  int t = threadIdx.x;
  int tx = t & 15, ty = t >> 4;
  for (int r = 0; r < 64; r++) {
    float w = (r < 32) ? Wf[r * 256 + t] : Wg[(r - 32) * 256 + t];
    Wt[t][r] = w;
  }
  float acc[4][4] = {};
  int n = t >> 2, cp = t & 3;
  for (int kc = 0; kc < 8; kc++) {
    __syncthreads();
#pragma unroll
    for (int r = 0; r < 2; r++) {
      int e = (r * 256 + t) * 4;
      int row = e >> 6, col = e & 63;
      *(float4*)&xl[row][col] =
          *(const float4*)(x + ((size_t)(b * NC + kc * 32 + row)) * NPIX + n0 + col);
    }
    __syncthreads();
    {
      u32 uu[4];
#pragma unroll
      for (int q = 0; q < 4; q++)
        uu[q] = cvtpk(xl[cp * 8 + 2 * q][n], xl[cp * 8 + 2 * q + 1][n]);
      *(uint4*)(xT + ((size_t)(b * NPIX) + n0 + n) * NC + kc * 32 + cp * 8) =
          make_uint4(uu[0], uu[1], uu[2], uu[3]);
    }
#pragma unroll
    for (int kk = 0; kk < 32; kk++) {
      float4 xv = *(const float4*)&xl[kk][tx * 4];
      float w0 = Wt[kc * 32 + kk][ty * 4 + 0];
      float w1 = Wt[kc * 32 + kk][ty * 4 + 1];
      float w2 = Wt[kc * 32 + kk][ty * 4 + 2];
      float w3 = Wt[kc * 32 + kk][ty * 4 + 3];
      acc[0][0] += w0 * xv.x; acc[0][1] += w0 * xv.y; acc[0][2] += w0 * xv.z; acc[0][3] += w0 * xv.w;
      acc[1][0] += w1 * xv.x; acc[1][1] += w1 * xv.y; acc[1][2] += w1 * xv.z; acc[1][3] += w1 * xv.w;
      acc[2][0] += w2 * xv.x; acc[2][1] += w2 * xv.y; acc[2][2] += w2 * xv.z; acc[2][3] += w2 * xv.w;
      acc[3][0] += w3 * xv.x; acc[3][1] += w3 * xv.y; acc[3][2] += w3 * xv.z; acc[3][3] += w3 * xv.w;
    }
  }
#pragma unroll
  for (int j = 0; j < 4; j++) {
    int o = ty * 4 + j;
    float bias = (o < 32) ? bf_[o] : bg_[o - 32];
#pragma unroll
    for (int vi = 0; vi < 4; vi++) tb[tx * 4 + vi][o] = acc[j][vi] + bias;
  }
  __syncthreads();
  int part = t & 3;
  // f half -> fragment-tiled fP
  {
    u32 ph[4], plo[4];
#pragma unroll
    for (int e = 0; e < 4; e++) {
      float v0 = tb[n][part * 8 + 2 * e + 0];
      float v1 = tb[n][part * 8 + 2 * e + 1];
      u16 h0 = f2bf(v0), h1 = f2bf(v1);
      u16 l0 = f2bf(v0 - bf2f(h0)), l1 = f2bf(v1 - bf2f(h1));
      ph[e] = (u32)h0 | ((u32)h1 << 16);
      plo[e] = (u32)l0 | ((u32)l1 << 16);
    }
    int jt_g = (n0 >> 4) + (n >> 4), r = n & 15;
    u16* dst = fP + ((size_t)(b * 256) + jt_g) * 1024 + r * 32 + part * 8;
    *(uint4*)dst = make_uint4(ph[0], ph[1], ph[2], ph[3]);
    *(uint4*)(dst + 512) = make_uint4(plo[0], plo[1], plo[2], plo[3]);
  }
  // g half -> flat gT
  {
    u32 ph[4], plo[4];
#pragma unroll
    for (int e = 0; e < 4; e++) {
      float v0 = tb[n][32 + part * 8 + 2 * e + 0];
      float v1 = tb[n][32 + part * 8 + 2 * e + 1];
      u16 h0 = f2bf(v0), h1 = f2bf(v1);
      u16 l0 = f2bf(v0 - bf2f(h0)), l1 = f2bf(v1 - bf2f(h1));
      ph[e] = (u32)h0 | ((u32)h1 << 16);
      plo[e] = (u32)l0 | ((u32)l1 << 16);
    }
    u16* dst = gT + ((size_t)(b * NPIX) + n0 + n) * 64 + part * 8;
    *(uint4*)dst = make_uint4(ph[0], ph[1], ph[2], ph[3]);
    *(uint4*)(dst + 32) = make_uint4(plo[0], plo[1], plo[2], plo[3]);
  }
}

// ---------------- K4: h projection -> h2[b][j>>5][c][j&31] bf16 ----------------
__global__ __launch_bounds__(256) void k_h(const u16* __restrict__ xT,
                                           const float* __restrict__ Wh,
                                           const float* __restrict__ bh,
                                           u16* __restrict__ h2) {
  __shared__ u16 At[128 * 32];
  __shared__ u16 Bt[128 * 32];
  int blk = blockIdx.x;
  int b = blk >> 6, r = blk & 63;
  int nt = r >> 1, ot = r & 1;
  int n0 = nt * 128, o0 = ot * 128;
  int t = threadIdx.x, lane = t & 63, w = t >> 6;
  int wr = w >> 1, wc = w & 1;
  int coll = lane & 15, cg = lane >> 4;
  f32x4 acc[4][4] = {};
  for (int kc = 0; kc < 8; kc++) {
    __syncthreads();
#pragma unroll
    for (int r2 = 0; r2 < 2; r2++) {
      int s = r2 * 256 + t;
      int row = s >> 2, slot = s & 3;
      int sw = (row ^ (row >> 2)) & 3;
      uint4 va = *(const uint4*)(xT + ((size_t)(b * NPIX + n0 + row)) * NC + kc * 32 + slot * 8);
      *(uint4*)((char*)At + row * 64 + ((slot ^ sw) * 16)) = va;
      const float* wsrc = Wh + (size_t)(o0 + row) * NC + kc * 32 + slot * 8;
      float4 w0 = *(const float4*)wsrc;
      float4 w1 = *(const float4*)(wsrc + 4);
      uint4 vb = make_uint4(cvtpk(w0.x, w0.y), cvtpk(w0.z, w0.w),
                            cvtpk(w1.x, w1.y), cvtpk(w1.z, w1.w));
      *(uint4*)((char*)Bt + row * 64 + ((slot ^ sw) * 16)) = vb;
    }
    __syncthreads();
    bfv8 af[4], bfr[4];
#pragma unroll
    for (int mi = 0; mi < 4; mi++) {
      int row = wr * 64 + mi * 16 + coll;
      int slot = cg ^ ((row ^ (row >> 2)) & 3);
      af[mi] = *(const bfv8*)((const char*)At + row * 64 + slot * 16);
    }
#pragma unroll
    for (int ni = 0; ni < 4; ni++) {
      int row = wc * 64 + ni * 16 + coll;
      int slot = cg ^ ((row ^ (row >> 2)) & 3);
      bfr[ni] = *(const bfv8*)((const char*)Bt + row * 64 + slot * 16);
    }
#pragma unroll
    for (int mi = 0; mi < 4; mi++)
#pragma unroll
      for (int ni = 0; ni < 4; ni++)
        acc[mi][ni] = __builtin_amdgcn_mfma_f32_16x16x32_bf16(af[mi], bfr[ni], acc[mi][ni], 0, 0, 0);
  }
#pragma unroll
  for (int ni = 0; ni < 4; ni++) {
    int o = o0 + wc * 64 + ni * 16 + coll;
    float bias = bh[o];
#pragma unroll
    for (int mi = 0; mi < 4; mi++) {
      int px = n0 + wr * 64 + mi * 16 + cg * 4;
      u32 lo = cvtpk(acc[mi][ni][0] + bias, acc[mi][ni][1] + bias);
      u32 hi = cvtpk(acc[mi][ni][2] + bias, acc[mi][ni][3] + bias);
      *(uint2*)(h2 + (((size_t)(b * 128) + (px >> 5)) * NC + o) * 32 + (px & 31)) =
          make_uint2(lo, hi);
    }
  }
}

// ---------------- K5: pass 1 partials — per (b, j-tile, i-slice): m,d ----------------
__global__ __launch_bounds__(256) void k_pass1(const u16* __restrict__ fP,
                                               const u16* __restrict__ gT,
                                               float2* __restrict__ pmd) {
  __shared__ u16 gs[64 * 64];
  int blk = blockIdx.x;
  int iq = blk & 7, jt = (blk >> 3) & 63, b = blk >> 9;
  int j0 = jt * 64, ibase = iq * 512;
  int t = threadIdx.x, lane = t & 63, w = t >> 6;
  int coll = lane & 15, cg = lane >> 4;
  const u16* fr = fP + ((size_t)(b * 256) + (j0 >> 4) + w) * 1024 + coll * 32 + cg * 8;
  bfv8 ah = *(const bfv8*)fr;
  bfv8 al = *(const bfv8*)(fr + 512);
  float m[4] = {-3e38f, -3e38f, -3e38f, -3e38f}, d[4] = {0.f, 0.f, 0.f, 0.f};
  int r0 = t >> 3, s0 = t & 7;
  uint4 v0 = *(const uint4*)(gT + ((size_t)(b * NPIX) + ibase + r0) * 64 + s0 * 8);
  uint4 v1 = *(const uint4*)(gT + ((size_t)(b * NPIX) + ibase + 32 + r0) * 64 + s0 * 8);
  for (int it2 = 0; it2 < 8; ++it2) {
    __syncthreads();
    *(uint4*)(&gs[r0 * 64 + ((s0 ^ (r0 & 7)) << 3)]) = v0;
    *(uint4*)(&gs[(32 + r0) * 64 + ((s0 ^ (r0 & 7)) << 3)]) = v1;
    __syncthreads();
    if (it2 < 7) {
      v0 = *(const uint4*)(gT + ((size_t)(b * NPIX) + ibase + (it2 + 1) * 64 + r0) * 64 + s0 * 8);
      v1 = *(const uint4*)(gT + ((size_t)(b * NPIX) + ibase + (it2 + 1) * 64 + 32 + r0) * 64 + s0 * 8);
    }
    float sv[4][4];
#pragma unroll
    for (int t4 = 0; t4 < 4; ++t4) {
      int row = t4 * 16 + coll;
      const u16* base = &gs[row * 64];
      bfv8 bh = *(const bfv8*)(base + ((cg ^ (row & 7)) << 3));
      bfv8 bl = *(const bfv8*)(base + (((4 + cg) ^ (row & 7)) << 3));
      f32x4 s = {0.f, 0.f, 0.f, 0.f};
      s = __builtin_amdgcn_mfma_f32_16x16x32_bf16(al, bh, s, 0, 0, 0);
      s = __builtin_amdgcn_mfma_f32_16x16x32_bf16(ah, bl, s, 0, 0, 0);
      s = __builtin_amdgcn_mfma_f32_16x16x32_bf16(ah, bh, s, 0, 0, 0);
      sv[t4][0] = s[0]; sv[t4][1] = s[1]; sv[t4][2] = s[2]; sv[t4][3] = s[3];
    }
#pragma unroll
    for (int r = 0; r < 4; ++r) {
      float ms = fmaxf(fmaxf(sv[0][r], sv[1][r]), fmaxf(sv[2][r], sv[3][r]));
      float nm = fmaxf(m[r], ms);
      d[r] = d[r] * __expf(m[r] - nm) + __expf(sv[0][r] - nm) + __expf(sv[1][r] - nm) +
             __expf(sv[2][r] - nm) + __expf(sv[3][r] - nm);
      m[r] = nm;
    }
  }
#pragma unroll
  for (int r = 0; r < 4; ++r) {
#pragma unroll
    for (int off = 1; off < 16; off <<= 1) {
      float m2 = __shfl_xor(m[r], off);
      float d2 = __shfl_xor(d[r], off);
      float nm = fmaxf(m[r], m2);
      d[r] = d[r] * __expf(m[r] - nm) + d2 * __expf(m2 - nm);
      m[r] = nm;
    }
  }
  if (coll == 0) {
#pragma unroll
    for (int r = 0; r < 4; ++r) {
      int j = j0 + w * 16 + cg * 4 + r;
      pmd[((size_t)(b * 8 + iq)) * NPIX + j] = make_float2(m[r], d[r]);
    }
  }
}

// ---------------- K5b: combine partials -> a_j = M*log2e + log2(D) ----------------
__global__ __launch_bounds__(256) void k_comb(const float2* __restrict__ pmd,
                                              float* __restrict__ aout) {
  int idx = blockIdx.x * 256 + threadIdx.x;  // 16384
  int b = idx >> 12, j = idx & 4095;
  float2 p[8];
  float M = -3e38f;
#pragma unroll
  for (int q = 0; q < 8; ++q) {
    p[q] = pmd[((size_t)(b * 8 + q)) * NPIX + j];
    M = fmaxf(M, p[q].x);
  }
  float D = 0.f;
#pragma unroll
  for (int q = 0; q < 8; ++q) D += p[q].y * __expf(p[q].x - M);
  aout[idx] = fmaf(M, LOG2E, __log2f(D));
}

// ---------------- K6: pass 2 — Opart[jq][b,c,i] (bf16), h in registers ----------------
__global__ __launch_bounds__(256, 2) void k_pass2(const u16* __restrict__ fP,
                                                  const u16* __restrict__ gT,
                                                  const u16* __restrict__ h2,
                                                  const float* __restrict__ arow,
                                                  u16* __restrict__ Opart) {
  // pl[2][4 waves][2KB] = 16KB; alds[2][64] floats at 16384; epilogue tbf alias
  __shared__ char smem[17408];
  int blk = blockIdx.x;
  int jq = blk & 1, it = (blk >> 1) & 63, b = blk >> 7;
  int i0 = it * 64, jbase = jq * 2048;
  int t = threadIdx.x, lane = t & 63, w = t >> 6;
  int coll = lane & 15, cg = lane >> 4;
  int cbase = w * 64;
  int swz = (coll & 7) << 4;
  // g B-frags (fixed): wave's i-subtile
  const u16* gr = gT + ((size_t)(b * NPIX) + i0 + w * 16 + coll) * 64 + cg * 8;
  bfv8 gh = *(const bfv8*)gr;
  bfv8 gl = *(const bfv8*)(gr + 32);
  f32x4 acc[4][4] = {};  // [ct (c-sub)][ni (i-sub)]
  // h A-frags: tiled layout, contiguous 1024B wave loads
  const u16* h2b = h2 + (((size_t)(b * 128) + (jbase >> 5)) * NC + cbase + coll) * 32 + cg * 8;
  bfv8 hv[4][2];
#pragma unroll
  for (int ct = 0; ct < 4; ++ct)
#pragma unroll
    for (int kb = 0; kb < 2; ++kb)
      hv[ct][kb] = *(const bfv8*)(h2b + (size_t)kb * 8192 + ct * 512);
  // f A-frags: tiled layout
  const u16* fPb = fP + ((size_t)(b * 256) + (jbase >> 4)) * 1024 + coll * 32 + cg * 8;
  bfv8 fh[4], fl[4];
#pragma unroll
  for (int jt2 = 0; jt2 < 4; ++jt2) {
    fh[jt2] = *(const bfv8*)(fPb + jt2 * 1024);
    fl[jt2] = *(const bfv8*)(fPb + jt2 * 1024 + 512);
  }
  float apre = 0.f;
  if (t < 64) ((float*)(smem + 16384))[t] = arow[b * NPIX + jbase + t];
  // QK(0)
  f32x4 s[4];
#pragma unroll
  for (int jt2 = 0; jt2 < 4; ++jt2) {
    f32x4 ss = {0.f, 0.f, 0.f, 0.f};
    ss = __builtin_amdgcn_mfma_f32_16x16x32_bf16(fl[jt2], gh, ss, 0, 0, 0);
    ss = __builtin_amdgcn_mfma_f32_16x16x32_bf16(fh[jt2], gl, ss, 0, 0, 0);
    ss = __builtin_amdgcn_mfma_f32_16x16x32_bf16(fh[jt2], gh, ss, 0, 0, 0);
    s[jt2] = ss;
  }
  // f(1), a(1)
#pragma unroll
  for (int jt2 = 0; jt2 < 4; ++jt2) {
    fh[jt2] = *(const bfv8*)(fPb + (4 + jt2) * 1024);
    fl[jt2] = *(const bfv8*)(fPb + (4 + jt2) * 1024 + 512);
  }
  if (t < 64) apre = arow[b * NPIX + jbase + 64 + t];
  __syncthreads();

  for (int jc = 0; jc < 32; ++jc) {
    int p = jc & 1;
    // ---- exp + P write ----
    const float* alds = (const float*)(smem + 16384) + p * 64;
#pragma unroll
    for (int jt2 = 0; jt2 < 4; ++jt2) {
      int jr = jt2 * 16 + cg * 4;
      float4 av = *(const float4*)&alds[jr];
      float p0 = exp2f(fmaf(s[jt2][0], LOG2E, -av.x));
      float p1 = exp2f(fmaf(s[jt2][1], LOG2E, -av.y));
      float p2 = exp2f(fmaf(s[jt2][2], LOG2E, -av.z));
      float p3 = exp2f(fmaf(s[jt2][3], LOG2E, -av.w));
      char* pb = smem + p * 8192 + w * 2048 + coll * 128;
      *(uint2*)(pb + ((jt2 * 32 + cg * 8) ^ swz)) =
          make_uint2(cvtpk(p0, p1), cvtpk(p2, p3));
    }
    if (t < 64) ((float*)(smem + 16384))[((jc + 1) & 1) * 64 + t] = apre;
    __syncthreads();
    // ---- PV phase ----
#pragma unroll
    for (int ni = 0; ni < 4; ++ni) {
      const char* pbr = smem + p * 8192 + ni * 2048 + coll * 128;
      bfv8 pa0 = *(const bfv8*)(pbr + ((cg * 16) ^ swz));
      bfv8 pa1 = *(const bfv8*)(pbr + ((64 + cg * 16) ^ swz));
#pragma unroll
      for (int ct = 0; ct < 4; ++ct) {
        acc[ct][ni] = __builtin_amdgcn_mfma_f32_16x16x32_bf16(hv[ct][0], pa0, acc[ct][ni], 0, 0, 0);
        acc[ct][ni] = __builtin_amdgcn_mfma_f32_16x16x32_bf16(hv[ct][1], pa1, acc[ct][ni], 0, 0, 0);
      }
    }
    if (jc < 31) {
      // next h frags
#pragma unroll
      for (int ct = 0; ct < 4; ++ct)
#pragma unroll
        for (int kb = 0; kb < 2; ++kb)
          hv[ct][kb] =
              *(const bfv8*)(h2b + (size_t)((jc + 1) * 2 + kb) * 8192 + ct * 512);
      // QK(jc+1) with f(jc+1)
#pragma unroll
      for (int jt2 = 0; jt2 < 4; ++jt2) {
        f32x4 ss = {0.f, 0.f, 0.f, 0.f};
        ss = __builtin_amdgcn_mfma_f32_16x16x32_bf16(fl[jt2], gh, ss, 0, 0, 0);
        ss = __builtin_amdgcn_mfma_f32_16x16x32_bf16(fh[jt2], gl, ss, 0, 0, 0);
        ss = __builtin_amdgcn_mfma_f32_16x16x32_bf16(fh[jt2], gh, ss, 0, 0, 0);
        s[jt2] = ss;
      }
      if (jc < 30) {
        // f(jc+2), a(jc+2)
#pragma unroll
        for (int jt2 = 0; jt2 < 4; ++jt2) {
          fh[jt2] = *(const bfv8*)(fPb + (size_t)((jc + 2) * 4 + jt2) * 1024);
          fl[jt2] = *(const bfv8*)(fPb + (size_t)((jc + 2) * 4 + jt2) * 1024 + 512);
        }
        if (t < 64) apre = arow[b * NPIX + jbase + (jc + 2) * 64 + t];
      }
    }
  }
  // ---- epilogue: per-wave transpose via LDS, write bf16 partials ----
  int rr = lane >> 2, part = lane & 3;
  for (int rd = 0; rd < 4; ++rd) {
    __syncthreads();
    float* tbf = (float*)smem;
#pragma unroll
    for (int ni = 0; ni < 4; ++ni)
#pragma unroll
      for (int r = 0; r < 4; ++r)
        tbf[(w * 16 + cg * 4 + r) * 68 + ni * 16 + coll] = acc[rd][ni][r];
    __syncthreads();
    const float* src = &((float*)smem)[(w * 16 + rr) * 68 + part * 16];
    u32 uu[8];
#pragma unroll
    for (int q = 0; q < 8; ++q) uu[q] = cvtpk(src[2 * q], src[2 * q + 1]);
    u16* op = Opart + (size_t)jq * TOT +
              ((size_t)(b * NC) + cbase + rd * 16 + rr) * NPIX + i0 + part * 16;
    *(uint4*)op = make_uint4(uu[0], uu[1], uu[2], uu[3]);
    *(uint4*)(op + 8) = make_uint4(uu[4], uu[5], uu[6], uu[7]);
  }
}

// ---------------- K7: reduce partials + residual ----------------
__global__ __launch_bounds__(256) void k_reduce(const u16* __restrict__ Opart,
                                                const float* __restrict__ x,
                                                const float* __restrict__ gamma,
                                                float* __restrict__ out) {
  int i = (blockIdx.x * 256 + threadIdx.x) * 4;
  uint2 a = *(const uint2*)(Opart + i);
  uint2 c = *(const uint2*)(Opart + TOT + i);
  float4 xv = *(const float4*)(x + i);
  float gam = gamma[0];
  float4 ov;
  ov.x = gam * (bf2f((u16)(a.x & 0xffff)) + bf2f((u16)(c.x & 0xffff))) + xv.x;
  ov.y = gam * (bf2f((u16)(a.x >> 16)) + bf2f((u16)(c.x >> 16))) + xv.y;
  ov.z = gam * (bf2f((u16)(a.y & 0xffff)) + bf2f((u16)(c.y & 0xffff))) + xv.z;
  ov.w = gam * (bf2f((u16)(a.y >> 16)) + bf2f((u16)(c.y >> 16))) + xv.w;
  *(float4*)(out + i) = ov;
}

extern "C" void kernel_launch(void* const* d_in, const int* in_sizes, int n_in,
                              void* d_out, int out_size, void* d_ws, size_t ws_size,
                              hipStream_t stream) {
  (void)in_sizes; (void)n_in; (void)out_size; (void)ws_size;
  const float* x = (const float*)d_in[0];
  const float* Wf = (const float*)d_in[1];
  const float* bf_ = (const float*)d_in[2];
  const float* Wg = (const float*)d_in[3];
  const float* bg_ = (const float*)d_in[4];
  const float* Wh = (const float*)d_in[5];
  const float* bh = (const float*)d_in[6];
  const float* gamma = (const float*)d_in[7];
  float* out = (float*)d_out;
  char* ws = (char*)d_ws;
  const size_t M1 = 1u << 20;
  // [0,16M): xT (8MB, dead after k_h) then Opart (2 bf16 partials, 16MB)
  u16* xT = (u16*)ws;
  u16* Opart = (u16*)ws;
  u16* h2 = (u16*)(ws + 17 * M1);
  u16* fP = (u16*)(ws + 25 * M1);
  u16* gT = (u16*)(ws + 27 * M1);
  float* aout = (float*)(ws + 29 * M1);                // 64KB
  float2* pmd = (float2*)(ws + 29 * M1 + (1u << 17));  // 1MB

  k_fg<<<256, 256, 0, stream>>>(x, Wf, bf_, Wg, bg_, fP, gT, xT);
  k_pass1<<<2048, 256, 0, stream>>>(fP, gT, pmd);
  k_h<<<256, 256, 0, stream>>>(xT, Wh, bh, h2);
  k_comb<<<64, 256, 0, stream>>>(pmd, aout);
  k_pass2<<<512, 256, 0, stream>>>(fP, gT, h2, aout, Opart);
  k_reduce<<<4096, 256, 0, stream>>>(Opart, x, gamma, out);
}